// Round 1
// baseline (388.611 us; speedup 1.0000x reference)
//
#include <hip/hip_runtime.h>
#include <hip/hip_fp16.h>
#include <math.h>

#define NN 50000
#define NE 800000
#define NG 512
#define NET (NE + NN)            // edges + self loops
#define NT2 ((2 * NN + 63) / 64) // 1563 64-node tiles over both branches
#define GN4 ((2 * NN + 3) / 4)   // wave-per-node grids
#define GN8 ((2 * NN + 7) / 8)   // 2-dst-per-wave gather grids
#define NS 68                    // feature-major LDS stride (floats)

// bucket-sort CSR build
#define SLICE 512                        // dst nodes per slice
#define NSL ((NN + SLICE - 1) / SLICE)   // 98 slices per branch
#define CHK 4096                         // edges per chunk
#define NCK ((NET + CHK - 1) / CHK)      // 208 chunks per branch
#define CAP 10240                        // LDS csr buffer per slice

typedef unsigned short u16;

__device__ __forceinline__ float wsum64(float v) {
#pragma unroll
    for (int o = 32; o > 0; o >>= 1) v += __shfl_down(v, o, 64);
    return v;
}

__device__ __forceinline__ float fast_tanh(float x) {
    return 1.f - 2.f / (__expf(2.f * x) + 1.f);
}

// ---------------- CSR build: atomic-free two-level bucket sort ----------------

__global__ __launch_bounds__(256) void k_hist(const int* __restrict__ eia,
                                              const int* __restrict__ eib,
                                              int* __restrict__ cnts) {
    __shared__ int h[NSL];
    int b = blockIdx.x;
    int br = b >= NCK, c = b - (br ? NCK : 0);
    int t = threadIdx.x;
    for (int i = t; i < NSL; i += 256) h[i] = 0;
    __syncthreads();
    const int* ei = br ? eib : eia;
    int e0 = c * CHK, e1 = e0 + CHK; if (e1 > NET) e1 = NET;
    for (int e = e0 + t; e < e1; e += 256) {
        int d = (e < NE) ? __builtin_nontemporal_load(&ei[NE + e]) : (e - NE);
        atomicAdd(&h[d >> 9], 1);
    }
    __syncthreads();
    for (int i = t; i < NSL; i += 256) cnts[(br * NSL + i) * NCK + c] = h[i];
}

__global__ __launch_bounds__(64) void k_off1(int* __restrict__ cnts,
                                             int* __restrict__ sliceBase) {
    int b = blockIdx.x;                  // 2*NSL
    int br = b >= NSL, s = b - (br ? NSL : 0);
    int lane = threadIdx.x;
    int* row = cnts + (br * NSL + s) * NCK;
    int run = 0;
    for (int c0 = 0; c0 < NCK; c0 += 64) {
        int c = c0 + lane;
        int v = (c < NCK) ? row[c] : 0;
        int orig = v;
#pragma unroll
        for (int o = 1; o < 64; o <<= 1) {
            int tv = __shfl_up(v, o, 64);
            if (lane >= o) v += tv;
        }
        if (c < NCK) row[c] = run + v - orig;
        run += __shfl(v, 63, 64);
    }
    if (lane == 0) sliceBase[br * (NSL + 1) + s] = run;
}

__global__ void k_off2(int* __restrict__ sliceBase, int* __restrict__ rowptr2,
                       float* __restrict__ pool) {
    int t = threadIdx.x;  // 256
    for (int i = t; i < 4 * NG; i += 256) pool[i] = 0.f;
    if (t < 2) {
        int* sb = sliceBase + t * (NSL + 1);
        int run = 0;
        for (int s = 0; s < NSL; s++) { int v = sb[s]; sb[s] = run; run += v; }
        sb[NSL] = run;
        rowptr2[t * (NN + 1) + NN] = run;
    }
}

__global__ __launch_bounds__(256) void k_bucket(const int* __restrict__ eia,
                                                const int* __restrict__ eib,
                                                const int* __restrict__ cnts,
                                                const int* __restrict__ sliceBase,
                                                unsigned int* __restrict__ staging) {
    __shared__ int cur[NSL];
    int b = blockIdx.x;
    int br = b >= NCK, c = b - (br ? NCK : 0);
    int t = threadIdx.x;
    for (int i = t; i < NSL; i += 256)
        cur[i] = cnts[(br * NSL + i) * NCK + c] + sliceBase[br * (NSL + 1) + i];
    __syncthreads();
    const int* ei = br ? eib : eia;
    unsigned int* stg = staging + (size_t)br * NET;
    int e0 = c * CHK, e1 = e0 + CHK; if (e1 > NET) e1 = NET;
    for (int e = e0 + t; e < e1; e += 256) {
        int d, s;
        if (e < NE) {
            d = __builtin_nontemporal_load(&ei[NE + e]);
            s = __builtin_nontemporal_load(&ei[e]);
        } else { d = e - NE; s = d; }
        int pos = atomicAdd(&cur[d >> 9], 1);   // LDS atomic
        stg[pos] = ((unsigned int)(d & 511) << 16) | (unsigned int)s;
    }
}

__global__ __launch_bounds__(512) void k_slice(const unsigned int* __restrict__ staging,
                                               const int* __restrict__ sliceBase,
                                               int* __restrict__ rowptr2,
                                               float* __restrict__ dinv2,
                                               u16* __restrict__ csr2) {
    __shared__ int sc[512];
    __shared__ int cur[512];
    __shared__ u16 buf[CAP];
    int b = blockIdx.x;
    int br = b >= NSL, sl = b - (br ? NSL : 0);
    int t = threadIdx.x;
    const int* sb = sliceBase + br * (NSL + 1);
    int base = sb[sl], m = sb[sl + 1] - base;
    const unsigned int* st = staging + (size_t)br * NET + base;
    cur[t] = 0;
    __syncthreads();
    for (int i = t; i < m; i += 512) atomicAdd(&cur[st[i] >> 16], 1);
    __syncthreads();
    int v = cur[t];
    sc[t] = v;
    __syncthreads();
    for (int o = 1; o < 512; o <<= 1) {
        int add = (t >= o) ? sc[t - o] : 0;
        __syncthreads();
        sc[t] += add;
        __syncthreads();
    }
    int excl = sc[t] - v;
    int node = sl * SLICE + t;
    if (node < NN) {
        rowptr2[br * (NN + 1) + node] = base + excl;
        dinv2[br * NN + node] = v > 0 ? rsqrtf((float)v) : 0.f;
    }
    cur[t] = excl;
    __syncthreads();
    for (int i = t; i < m; i += 512) {
        unsigned int e = st[i];
        int pos = atomicAdd(&cur[e >> 16], 1);
        if (pos < CAP) buf[pos] = (u16)(e & 0xffffu);
    }
    __syncthreads();
    u16* out = csr2 + (size_t)br * NET + base;
    int mm = m < CAP ? m : CAP;
    for (int i = t; i < mm; i += 512) out[i] = buf[i];
}

// ---------------- node-level kernels (node id in [0,2*NN)) ----

__global__ void k_gat_input(const float* __restrict__ xa, const float* __restrict__ xb,
                            const float* __restrict__ Wg,
                            const float* __restrict__ avs, const float* __restrict__ avd,
                            __half* __restrict__ A, float* __restrict__ als,
                            float* __restrict__ ald) {
    __shared__ float sW[9 * 64];
    __shared__ float sas[64], sad[64];
    int t = threadIdx.x;
    for (int i = t; i < 9 * 64; i += 256) sW[i] = Wg[i];
    if (t < 64) { sas[t] = avs[t]; sad[t] = avd[t]; }
    __syncthreads();
    int n = blockIdx.x * 4 + (t >> 6);
    int u = t & 63;
    if (n >= 2 * NN) return;
    const float* xp = (n < NN) ? &xa[(size_t)n * 9] : &xb[(size_t)(n - NN) * 9];
    float h = 0.f;
#pragma unroll
    for (int f = 0; f < 9; f++) h += xp[f] * sW[f * 64 + u];
    A[(size_t)n * 64 + u] = __float2half(h);
    float ps = wsum64(h * sas[u]);
    float pd = wsum64(h * sad[u]);
    if (u == 0) { als[n] = ps; ald[n] = pd; }
}

// GAT gather, 2 dsts per wave: lanes 0-31 -> dst0 (feats as half2), 32-63 -> dst1.
// (s,w) are half-wave-uniform: all lanes compute them redundantly from uniform
// (L1-broadcast) loads -- no shfl, no wave reduce. 4-deep unroll gives 4
// independent gather-load chains per half-wave for latency hiding.
// No max-stab (|e|<~25, fp32-safe).
__global__ __launch_bounds__(256) void k_gat_csr(
        const int* __restrict__ rowptr2, const u16* __restrict__ csr2,
        const float* __restrict__ als, const float* __restrict__ ald,
        const __half* __restrict__ A, const float* __restrict__ bias,
        __half* __restrict__ B) {
    int u = threadIdx.x & 63;
    int half = u >> 5, lu = u & 31;
    int dg = blockIdx.x * 8 + (threadIdx.x >> 6) * 2 + half;
    if (dg >= 2 * NN) return;
    int br = dg >= NN;
    int d = dg - br * NN;
    const int* rp = rowptr2 + br * (NN + 1);
    const u16* cs = csr2 + br * NET;
    int nb = br * NN;
    int beg = rp[d], end = rp[d + 1];
    float ad = ald[dg];
    const __half2* Ap = (const __half2*)A;
    float ax0 = 0.f, ay0 = 0.f, ax1 = 0.f, ay1 = 0.f;
    float ax2 = 0.f, ay2 = 0.f, ax3 = 0.f, ay3 = 0.f;
    float den = 0.f;
    int j = beg;
    for (; j + 4 <= end; j += 4) {
        int s0 = nb + cs[j];
        int s1 = nb + cs[j + 1];
        int s2 = nb + cs[j + 2];
        int s3 = nb + cs[j + 3];
        float v0 = als[s0] + ad;
        float v1 = als[s1] + ad;
        float v2 = als[s2] + ad;
        float v3 = als[s3] + ad;
        float w0 = __expf(fmaxf(v0, 0.2f * v0));
        float w1 = __expf(fmaxf(v1, 0.2f * v1));
        float w2 = __expf(fmaxf(v2, 0.2f * v2));
        float w3 = __expf(fmaxf(v3, 0.2f * v3));
        den += (w0 + w1) + (w2 + w3);
        float2 f0 = __half22float2(Ap[(size_t)s0 * 32 + lu]);
        float2 f1 = __half22float2(Ap[(size_t)s1 * 32 + lu]);
        float2 f2 = __half22float2(Ap[(size_t)s2 * 32 + lu]);
        float2 f3 = __half22float2(Ap[(size_t)s3 * 32 + lu]);
        ax0 += f0.x * w0; ay0 += f0.y * w0;
        ax1 += f1.x * w1; ay1 += f1.y * w1;
        ax2 += f2.x * w2; ay2 += f2.y * w2;
        ax3 += f3.x * w3; ay3 += f3.y * w3;
    }
    for (; j < end; j++) {
        int s = nb + cs[j];
        float v = als[s] + ad;
        float w = __expf(fmaxf(v, 0.2f * v));
        den += w;
        float2 f = __half22float2(Ap[(size_t)s * 32 + lu]);
        ax0 += f.x * w; ay0 += f.y * w;
    }
    float inv = 1.f / den;   // den uniform across the half-wave
    float2 bb = *(const float2*)&bias[2 * lu];
    ((__half2*)B)[(size_t)dg * 32 + lu] =
        __floats2half2_rn(fast_tanh(((ax0 + ax1) + (ax2 + ax3)) * inv + bb.x),
                          fast_tanh(((ay0 + ay1) + (ay2 + ay3)) * inv + bb.y));
}

// Stage 64-node fp16 tile into LDS feature-major: sX[feat * NS + node].
// Global reads stay fully coalesced; LDS scatter is a one-time cost.
__device__ __forceinline__ void load_tile_FM(const __half* __restrict__ X, int base,
                                             float* sX, int t) {
    const __half2* X2 = (const __half2*)X;
    for (int i = t; i < 2048; i += 256) {
        int node = i >> 5, p = i & 31;
        float2 v;
        if (base + node < 2 * NN) v = __half22float2(X2[(size_t)(base + node) * 32 + p]);
        else v = make_float2(0.f, 0.f);
        sX[(2 * p) * NS + node] = v.x;
        sX[(2 * p + 1) * NS + node] = v.y;
    }
}

// Dense Y = dinv[n] * (X @ W), 64-node tile, 4x4 blocking, fp16 weights/IO.
// Feature-major sX: per k one ds_read_b128 (4 nodes) + one ds_read_b64 (4 wts).
__global__ __launch_bounds__(256) void k_lin_tile(
        const __half* __restrict__ X, const float* __restrict__ W,
        const float* __restrict__ dinv, __half* __restrict__ Y) {
    __shared__ __half sW[64 * 64];
    __shared__ float sX[64 * NS];
    int t = threadIdx.x;
    for (int i = t; i < 4096; i += 256) sW[i] = __float2half(W[i]);
    int base = blockIdx.x * 64;
    load_tile_FM(X, base, sX, t);
    __syncthreads();
    int tx = t & 15, ty = t >> 4;
    float acc[4][4];
#pragma unroll
    for (int i = 0; i < 4; i++)
#pragma unroll
        for (int j = 0; j < 4; j++) acc[i][j] = 0.f;
#pragma unroll 4
    for (int k = 0; k < 64; k++) {
        uint2 wraw = *(const uint2*)&sW[k * 64 + 4 * tx];
        float2 wa = __half22float2(*(__half2*)&wraw.x);
        float2 wb = __half22float2(*(__half2*)&wraw.y);
        float4 xv = *(const float4*)&sX[k * NS + 4 * ty];
        acc[0][0] += xv.x * wa.x; acc[0][1] += xv.x * wa.y; acc[0][2] += xv.x * wb.x; acc[0][3] += xv.x * wb.y;
        acc[1][0] += xv.y * wa.x; acc[1][1] += xv.y * wa.y; acc[1][2] += xv.y * wb.x; acc[1][3] += xv.y * wb.y;
        acc[2][0] += xv.z * wa.x; acc[2][1] += xv.z * wa.y; acc[2][2] += xv.z * wb.x; acc[2][3] += xv.z * wb.y;
        acc[3][0] += xv.w * wa.x; acc[3][1] += xv.w * wa.y; acc[3][2] += xv.w * wb.x; acc[3][3] += xv.w * wb.y;
    }
#pragma unroll
    for (int i = 0; i < 4; i++) {
        int n = base + 4 * ty + i;
        if (n < 2 * NN) {
            float dv = dinv[n];
            __half2* Y2 = (__half2*)&Y[(size_t)n * 64 + 4 * tx];
            Y2[0] = __floats2half2_rn(acc[i][0] * dv, acc[i][1] * dv);
            Y2[1] = __floats2half2_rn(acc[i][2] * dv, acc[i][3] * dv);
        }
    }
}

// GCN gather on pre-scaled Y, 2 dsts per wave (half2 features), uniform-scalar
// src indices, 4-deep independent gather chains.
__global__ __launch_bounds__(256) void k_gcn_gather(
        const int* __restrict__ rowptr2, const u16* __restrict__ csr2,
        const float* __restrict__ dinv, const __half* __restrict__ Y,
        const float* __restrict__ bias, __half* __restrict__ Bout) {
    int u = threadIdx.x & 63;
    int half = u >> 5, lu = u & 31;
    int dg = blockIdx.x * 8 + (threadIdx.x >> 6) * 2 + half;
    if (dg >= 2 * NN) return;
    int br = dg >= NN;
    int d = dg - br * NN;
    const int* rp = rowptr2 + br * (NN + 1);
    const u16* cs = csr2 + br * NET;
    int nb = br * NN;
    int beg = rp[d], end = rp[d + 1];
    const __half2* Yp = (const __half2*)Y;
    float ax0 = 0.f, ay0 = 0.f, ax1 = 0.f, ay1 = 0.f;
    float ax2 = 0.f, ay2 = 0.f, ax3 = 0.f, ay3 = 0.f;
    int j = beg;
    for (; j + 4 <= end; j += 4) {
        int s0 = nb + cs[j];
        int s1 = nb + cs[j + 1];
        int s2 = nb + cs[j + 2];
        int s3 = nb + cs[j + 3];
        float2 f0 = __half22float2(Yp[(size_t)s0 * 32 + lu]);
        float2 f1 = __half22float2(Yp[(size_t)s1 * 32 + lu]);
        float2 f2 = __half22float2(Yp[(size_t)s2 * 32 + lu]);
        float2 f3 = __half22float2(Yp[(size_t)s3 * 32 + lu]);
        ax0 += f0.x; ay0 += f0.y;
        ax1 += f1.x; ay1 += f1.y;
        ax2 += f2.x; ay2 += f2.y;
        ax3 += f3.x; ay3 += f3.y;
    }
    for (; j < end; j++) {
        int s = nb + cs[j];
        float2 f = __half22float2(Yp[(size_t)s * 32 + lu]);
        ax0 += f.x; ay0 += f.y;
    }
    float dv = dinv[dg];
    float2 bb = *(const float2*)&bias[2 * lu];
    ((__half2*)Bout)[(size_t)dg * 32 + lu] =
        __floats2half2_rn(fast_tanh(((ax0 + ax1) + (ax2 + ax3)) * dv + bb.x),
                          fast_tanh(((ay0 + ay1) + (ay2 + ay3)) * dv + bb.y));
}

// MLP (64->64 tanh ->32 tanh ->1) + mean-pool. Feature-major LDS, fp16 weights,
// segmented-run pool atomics.
__global__ __launch_bounds__(256) void k_mlp_pool(
        const __half* __restrict__ X,
        const int* __restrict__ batch_a, const int* __restrict__ batch_b,
        const float* __restrict__ W1, const float* __restrict__ b1,
        const float* __restrict__ W2, const float* __restrict__ b2,
        const float* __restrict__ W3, const float* __restrict__ b3,
        float* __restrict__ pool) {
    __shared__ __half sW1[64 * 64];
    __shared__ __half sW2[64 * 32];
    __shared__ float sX[64 * NS];
    __shared__ float sP[64 * 9];
    __shared__ float sW3[32], sb1[64], sb2[32];
    __shared__ int sKey[64];
    __shared__ float sVal[64];
    int t = threadIdx.x;
    for (int i = t; i < 4096; i += 256) sW1[i] = __float2half(W1[i]);
    for (int i = t; i < 2048; i += 256) sW2[i] = __float2half(W2[i]);
    if (t < 64) sb1[t] = b1[t];
    if (t < 32) { sW3[t] = W3[t]; sb2[t] = b2[t]; }
    float bb3 = b3[0];
    int base = blockIdx.x * 64;
    load_tile_FM(X, base, sX, t);
    __syncthreads();
    int tx = t & 15, ty = t >> 4;
    float acc[4][4];
#pragma unroll
    for (int i = 0; i < 4; i++)
#pragma unroll
        for (int j = 0; j < 4; j++) acc[i][j] = sb1[4 * tx + j];
#pragma unroll 4
    for (int k = 0; k < 64; k++) {
        uint2 wraw = *(const uint2*)&sW1[k * 64 + 4 * tx];
        float2 wa = __half22float2(*(__half2*)&wraw.x);
        float2 wb = __half22float2(*(__half2*)&wraw.y);
        float4 xv = *(const float4*)&sX[k * NS + 4 * ty];
        acc[0][0] += xv.x * wa.x; acc[0][1] += xv.x * wa.y; acc[0][2] += xv.x * wb.x; acc[0][3] += xv.x * wb.y;
        acc[1][0] += xv.y * wa.x; acc[1][1] += xv.y * wa.y; acc[1][2] += xv.y * wb.x; acc[1][3] += xv.y * wb.y;
        acc[2][0] += xv.z * wa.x; acc[2][1] += xv.z * wa.y; acc[2][2] += xv.z * wb.x; acc[2][3] += xv.z * wb.y;
        acc[3][0] += xv.w * wa.x; acc[3][1] += xv.w * wa.y; acc[3][2] += xv.w * wb.x; acc[3][3] += xv.w * wb.y;
    }
    __syncthreads();
    // tanh intermediate back to sX feature-major: row 4*tx+j, nodes 4*ty..4*ty+3
#pragma unroll
    for (int j = 0; j < 4; j++) {
        float4 o = make_float4(fast_tanh(acc[0][j]), fast_tanh(acc[1][j]),
                               fast_tanh(acc[2][j]), fast_tanh(acc[3][j]));
        *(float4*)&sX[(4 * tx + j) * NS + 4 * ty] = o;
    }
    __syncthreads();
    int tx2 = t & 7, ty2 = t >> 3;
    float a2_[2][4];
#pragma unroll
    for (int i = 0; i < 2; i++)
#pragma unroll
        for (int j = 0; j < 4; j++) a2_[i][j] = sb2[4 * tx2 + j];
#pragma unroll 4
    for (int k = 0; k < 64; k++) {
        uint2 wraw = *(const uint2*)&sW2[k * 32 + 4 * tx2];
        float2 wa = __half22float2(*(__half2*)&wraw.x);
        float2 wb = __half22float2(*(__half2*)&wraw.y);
        float2 xv = *(const float2*)&sX[k * NS + 2 * ty2];
        a2_[0][0] += xv.x * wa.x; a2_[0][1] += xv.x * wa.y; a2_[0][2] += xv.x * wb.x; a2_[0][3] += xv.x * wb.y;
        a2_[1][0] += xv.y * wa.x; a2_[1][1] += xv.y * wa.y; a2_[1][2] += xv.y * wb.x; a2_[1][3] += xv.y * wb.y;
    }
#pragma unroll
    for (int i = 0; i < 2; i++) {
        float p = fast_tanh(a2_[i][0]) * sW3[4 * tx2]
                + fast_tanh(a2_[i][1]) * sW3[4 * tx2 + 1]
                + fast_tanh(a2_[i][2]) * sW3[4 * tx2 + 2]
                + fast_tanh(a2_[i][3]) * sW3[4 * tx2 + 3];
        sP[(2 * ty2 + i) * 9 + tx2] = p;
    }
    __syncthreads();
    if (t < 64) {
        int n = base + t;
        bool valid = n < 2 * NN;
        int br = n >= NN;
        int g = valid ? (br ? batch_b[n - NN] : batch_a[n]) : -1;
        int key = valid ? (br * 4096 + g) : -1;
        float s0 = sP[t * 9 + 0] + sP[t * 9 + 1] + sP[t * 9 + 2] + sP[t * 9 + 3];
        float s1 = sP[t * 9 + 4] + sP[t * 9 + 5] + sP[t * 9 + 6] + sP[t * 9 + 7];
        sKey[t] = key;
        sVal[t] = s0 + s1 + bb3;
        if (valid && (t == 0 || sKey[t - 1] != key)) {
            float sum = 0.f;
            int cnt = 0;
            for (int j = t; j < 64 && sKey[j] == key; j++) { sum += sVal[j]; cnt++; }
            float* bin = pool + br * 2 * NG;
            atomicAdd(&bin[g], sum);
            atomicAdd(&bin[NG + g], (float)cnt);
        }
    }
}

// pool layout: [sa(NG), ca(NG), sb(NG), cb(NG)]
__global__ void k_final(const float* __restrict__ pool, float* __restrict__ out) {
    int g = blockIdx.x * 256 + threadIdx.x;
    if (g >= NG) return;
    float ua = pool[g] / fmaxf(pool[NG + g], 1.f);
    float ub = pool[2 * NG + g] / fmaxf(pool[3 * NG + g], 1.f);
    float z = ub - ua;
    out[g] = 1.f / (1.f + __expf(-z));
}

extern "C" void kernel_launch(void* const* d_in, const int* in_sizes, int n_in,
                              void* d_out, int out_size, void* d_ws, size_t ws_size,
                              hipStream_t stream) {
    const float* x_a = (const float*)d_in[0];
    const float* x_b = (const float*)d_in[1];
    const int* ei_a = (const int*)d_in[2];
    const int* ei_b = (const int*)d_in[3];
    const int* batch_a = (const int*)d_in[4];
    const int* batch_b = (const int*)d_in[5];
    const float* Wg   = (const float*)d_in[6];
    const float* avs  = (const float*)d_in[7];
    const float* avd  = (const float*)d_in[8];
    const float* bg   = (const float*)d_in[9];
    const float* Wgcn = (const float*)d_in[10];
    const float* bgcn = (const float*)d_in[11];
    const float* W1 = (const float*)d_in[12];
    const float* b1 = (const float*)d_in[13];
    const float* W2 = (const float*)d_in[14];
    const float* b2 = (const float*)d_in[15];
    const float* W3 = (const float*)d_in[16];
    const float* b3 = (const float*)d_in[17];

    char* w = (char*)d_ws;
    __half* A2 = (__half*)w;          w += (size_t)2 * NN * 64 * 2;   // 12.8 MB
    __half* B2 = (__half*)w;          w += (size_t)2 * NN * 64 * 2;   // 12.8 MB
    float* als2 = (float*)w;          w += (size_t)2 * NN * 4;
    float* ald2 = (float*)w;          w += (size_t)2 * NN * 4;
    float* dinv2 = (float*)w;         w += (size_t)2 * NN * 4;
    float* pool = (float*)w;          w += (size_t)4 * NG * 4;
    int* rowptr2 = (int*)w;           w += (size_t)2 * (NN + 1) * 4;
    int* cnts = (int*)w;              w += (size_t)2 * NSL * NCK * 4; // 163 KB
    int* sliceBase = (int*)w;         w += (size_t)2 * (NSL + 1) * 4;
    u16* csr2 = (u16*)w;
    // staging (2*NET u32 = 6.8 MB) aliases A2: dead before k_gat_input writes A2
    unsigned int* staging = (unsigned int*)A2;

    dim3 blk(256);

    // CSR build: atomic-free bucket sort
    k_hist<<<2 * NCK, blk, 0, stream>>>(ei_a, ei_b, cnts);
    k_off1<<<2 * NSL, dim3(64), 0, stream>>>(cnts, sliceBase);
    k_off2<<<1, blk, 0, stream>>>(sliceBase, rowptr2, pool);
    k_bucket<<<2 * NCK, blk, 0, stream>>>(ei_a, ei_b, cnts, sliceBase, staging);
    k_slice<<<2 * NSL, dim3(512), 0, stream>>>(staging, sliceBase, rowptr2, dinv2, csr2);

    k_gat_input<<<GN4, blk, 0, stream>>>(x_a, x_b, Wg, avs, avd, A2, als2, ald2);
    k_gat_csr<<<GN8, blk, 0, stream>>>(rowptr2, csr2, als2, ald2, A2, bg, B2);
    k_lin_tile<<<NT2, blk, 0, stream>>>(B2, Wgcn, dinv2, A2);
    k_gcn_gather<<<GN8, blk, 0, stream>>>(rowptr2, csr2, dinv2, A2, bgcn, B2);
    k_lin_tile<<<NT2, blk, 0, stream>>>(B2, Wgcn + 64 * 64, dinv2, A2);
    k_gcn_gather<<<GN8, blk, 0, stream>>>(rowptr2, csr2, dinv2, A2, bgcn + 64, B2);
    k_mlp_pool<<<NT2, blk, 0, stream>>>(B2, batch_a, batch_b, W1, b1, W2, b2, W3, b3, pool);

    k_final<<<(NG + 255) / 256, blk, 0, stream>>>(pool, (float*)d_out);
}

// Round 2
// 355.132 us; speedup vs baseline: 1.0943x; 1.0943x over previous
//
#include <hip/hip_runtime.h>
#include <hip/hip_fp16.h>
#include <math.h>

#define NN 50000
#define NE 800000
#define NG 512
#define NET (NE + NN)            // edges + self loops
#define NT2 ((2 * NN + 63) / 64) // 1563 64-node tiles over both branches
#define GN4 ((2 * NN + 3) / 4)   // wave-per-node grids
#define GN8 ((2 * NN + 7) / 8)   // 2-dst-per-wave grids
#define GN32 ((2 * NN + 31) / 32) // 8-dst-per-wave gather grids (3125, exact)
#define NS 68                    // feature-major LDS stride (floats)

// bucket-sort CSR build
#define SLICE 512                        // dst nodes per slice
#define NSL ((NN + SLICE - 1) / SLICE)   // 98 slices per branch
#define CHK 4096                         // edges per chunk
#define NCK ((NET + CHK - 1) / CHK)      // 208 chunks per branch
#define CAP 10240                        // LDS csr buffer per slice

typedef unsigned short u16;

__device__ __forceinline__ float wsum64(float v) {
#pragma unroll
    for (int o = 32; o > 0; o >>= 1) v += __shfl_down(v, o, 64);
    return v;
}

__device__ __forceinline__ float fast_tanh(float x) {
    return 1.f - 2.f / (__expf(2.f * x) + 1.f);
}

// ---------------- CSR build: atomic-free two-level bucket sort ----------------

__global__ __launch_bounds__(256) void k_hist(const int* __restrict__ eia,
                                              const int* __restrict__ eib,
                                              int* __restrict__ cnts) {
    __shared__ int h[NSL];
    int b = blockIdx.x;
    int br = b >= NCK, c = b - (br ? NCK : 0);
    int t = threadIdx.x;
    for (int i = t; i < NSL; i += 256) h[i] = 0;
    __syncthreads();
    const int* ei = br ? eib : eia;
    int e0 = c * CHK, e1 = e0 + CHK; if (e1 > NET) e1 = NET;
    for (int e = e0 + t; e < e1; e += 256) {
        int d = (e < NE) ? __builtin_nontemporal_load(&ei[NE + e]) : (e - NE);
        atomicAdd(&h[d >> 9], 1);
    }
    __syncthreads();
    for (int i = t; i < NSL; i += 256) cnts[(br * NSL + i) * NCK + c] = h[i];
}

__global__ __launch_bounds__(64) void k_off1(int* __restrict__ cnts,
                                             int* __restrict__ sliceBase) {
    int b = blockIdx.x;                  // 2*NSL
    int br = b >= NSL, s = b - (br ? NSL : 0);
    int lane = threadIdx.x;
    int* row = cnts + (br * NSL + s) * NCK;
    int run = 0;
    for (int c0 = 0; c0 < NCK; c0 += 64) {
        int c = c0 + lane;
        int v = (c < NCK) ? row[c] : 0;
        int orig = v;
#pragma unroll
        for (int o = 1; o < 64; o <<= 1) {
            int tv = __shfl_up(v, o, 64);
            if (lane >= o) v += tv;
        }
        if (c < NCK) row[c] = run + v - orig;
        run += __shfl(v, 63, 64);
    }
    if (lane == 0) sliceBase[br * (NSL + 1) + s] = run;
}

__global__ void k_off2(int* __restrict__ sliceBase, int* __restrict__ rowptr2,
                       float* __restrict__ pool) {
    int t = threadIdx.x;  // 256
    for (int i = t; i < 4 * NG; i += 256) pool[i] = 0.f;
    if (t < 2) {
        int* sb = sliceBase + t * (NSL + 1);
        int run = 0;
        for (int s = 0; s < NSL; s++) { int v = sb[s]; sb[s] = run; run += v; }
        sb[NSL] = run;
        rowptr2[t * (NN + 1) + NN] = run;
    }
}

__global__ __launch_bounds__(256) void k_bucket(const int* __restrict__ eia,
                                                const int* __restrict__ eib,
                                                const int* __restrict__ cnts,
                                                const int* __restrict__ sliceBase,
                                                unsigned int* __restrict__ staging) {
    __shared__ int cur[NSL];
    int b = blockIdx.x;
    int br = b >= NCK, c = b - (br ? NCK : 0);
    int t = threadIdx.x;
    for (int i = t; i < NSL; i += 256)
        cur[i] = cnts[(br * NSL + i) * NCK + c] + sliceBase[br * (NSL + 1) + i];
    __syncthreads();
    const int* ei = br ? eib : eia;
    unsigned int* stg = staging + (size_t)br * NET;
    int e0 = c * CHK, e1 = e0 + CHK; if (e1 > NET) e1 = NET;
    for (int e = e0 + t; e < e1; e += 256) {
        int d, s;
        if (e < NE) {
            d = __builtin_nontemporal_load(&ei[NE + e]);
            s = __builtin_nontemporal_load(&ei[e]);
        } else { d = e - NE; s = d; }
        int pos = atomicAdd(&cur[d >> 9], 1);   // LDS atomic
        stg[pos] = ((unsigned int)(d & 511) << 16) | (unsigned int)s;
    }
}

__global__ __launch_bounds__(512) void k_slice(const unsigned int* __restrict__ staging,
                                               const int* __restrict__ sliceBase,
                                               int* __restrict__ rowptr2,
                                               float* __restrict__ dinv2,
                                               u16* __restrict__ csr2) {
    __shared__ int sc[512];
    __shared__ int cur[512];
    __shared__ u16 buf[CAP];
    int b = blockIdx.x;
    int br = b >= NSL, sl = b - (br ? NSL : 0);
    int t = threadIdx.x;
    const int* sb = sliceBase + br * (NSL + 1);
    int base = sb[sl], m = sb[sl + 1] - base;
    const unsigned int* st = staging + (size_t)br * NET + base;
    cur[t] = 0;
    __syncthreads();
    for (int i = t; i < m; i += 512) atomicAdd(&cur[st[i] >> 16], 1);
    __syncthreads();
    int v = cur[t];
    sc[t] = v;
    __syncthreads();
    for (int o = 1; o < 512; o <<= 1) {
        int add = (t >= o) ? sc[t - o] : 0;
        __syncthreads();
        sc[t] += add;
        __syncthreads();
    }
    int excl = sc[t] - v;
    int node = sl * SLICE + t;
    if (node < NN) {
        rowptr2[br * (NN + 1) + node] = base + excl;
        dinv2[br * NN + node] = v > 0 ? rsqrtf((float)v) : 0.f;
    }
    cur[t] = excl;
    __syncthreads();
    for (int i = t; i < m; i += 512) {
        unsigned int e = st[i];
        int pos = atomicAdd(&cur[e >> 16], 1);
        if (pos < CAP) buf[pos] = (u16)(e & 0xffffu);
    }
    __syncthreads();
    u16* out = csr2 + (size_t)br * NET + base;
    int mm = m < CAP ? m : CAP;
    for (int i = t; i < mm; i += 512) out[i] = buf[i];
}

// ---------------- node-level kernels (node id in [0,2*NN)) ----

__global__ void k_gat_input(const float* __restrict__ xa, const float* __restrict__ xb,
                            const float* __restrict__ Wg,
                            const float* __restrict__ avs, const float* __restrict__ avd,
                            __half* __restrict__ A, float* __restrict__ als,
                            float* __restrict__ ald) {
    __shared__ float sW[9 * 64];
    __shared__ float sas[64], sad[64];
    int t = threadIdx.x;
    for (int i = t; i < 9 * 64; i += 256) sW[i] = Wg[i];
    if (t < 64) { sas[t] = avs[t]; sad[t] = avd[t]; }
    __syncthreads();
    int n = blockIdx.x * 4 + (t >> 6);
    int u = t & 63;
    if (n >= 2 * NN) return;
    const float* xp = (n < NN) ? &xa[(size_t)n * 9] : &xb[(size_t)(n - NN) * 9];
    float h = 0.f;
#pragma unroll
    for (int f = 0; f < 9; f++) h += xp[f] * sW[f * 64 + u];
    A[(size_t)n * 64 + u] = __float2half(h);
    float ps = wsum64(h * sas[u]);
    float pd = wsum64(h * sad[u]);
    if (u == 0) { als[n] = ps; ald[n] = pd; }
}

// Normalized edge weights, CSR order: wn[j] = exp(lrelu(als[src]+ald[dst]))/den.
// Half-wave per dst, lane-parallel over edges (1 exp/edge). No max-stab
// (|e|<~25, fp32-safe; same as prior passing versions).
__global__ __launch_bounds__(256) void k_edgew(
        const int* __restrict__ rowptr2, const u16* __restrict__ csr2,
        const float* __restrict__ als, const float* __restrict__ ald,
        float* __restrict__ wn) {
    int u = threadIdx.x & 63;
    int lu = u & 31;
    int dg = blockIdx.x * 8 + (threadIdx.x >> 6) * 2 + (u >> 5);
    if (dg >= 2 * NN) return;
    int br = dg >= NN;
    int d = dg - br * NN;
    const int* rp = rowptr2 + br * (NN + 1);
    const u16* cs = csr2 + br * NET;
    float* wp = wn + (size_t)br * NET;
    int nb = br * NN;
    int beg = rp[d], end = rp[d + 1];
    float ad = ald[dg];
    float den = 0.f;
    for (int c = beg + lu; c < end; c += 32) {
        int s = nb + cs[c];
        float v = als[s] + ad;
        float w = __expf(fmaxf(v, 0.2f * v));
        den += w;
        wp[c] = w;
    }
#pragma unroll
    for (int o = 16; o > 0; o >>= 1) den += __shfl_down(den, o, 32);
    den = __shfl(den, 0, 32);
    float inv = 1.f / den;
    for (int c = beg + lu; c < end; c += 32) wp[c] *= inv;
}

// 8 halfs of a feature row, weighted-accumulated into 8 f32.
__device__ __forceinline__ void fma8(float* acc, float4 f, float w) {
    const __half2* h = (const __half2*)&f;
#pragma unroll
    for (int p = 0; p < 4; p++) {
        float2 v = __half22float2(h[p]);
        acc[2 * p]     += v.x * w;
        acc[2 * p + 1] += v.y * w;
    }
}

// GAT gather with precomputed normalized weights. 8 dsts per wave: lane-group
// g (8 lanes) owns dst g; lane li within group covers feats [8li, 8li+8) as one
// 16B dwordx4 load per edge (one wave load instr = 8 rows). Masked 4-wide
// iterations (clamped idx, w=0) -- no scalar tail, exec-mask divergence only
// across groups' iteration counts.
__global__ __launch_bounds__(256) void k_gat_gather8(
        const int* __restrict__ rowptr2, const u16* __restrict__ csr2,
        const float* __restrict__ wn, const __half* __restrict__ A,
        const float* __restrict__ bias, __half* __restrict__ B) {
    int lane = threadIdx.x & 63;
    int grp = lane >> 3, li = lane & 7;
    int dg = blockIdx.x * 32 + (threadIdx.x >> 6) * 8 + grp;  // grid exact: 3125*32=100000
    int br = dg >= NN;
    int d = dg - br * NN;
    const int* rp = rowptr2 + br * (NN + 1);
    const u16* cs = csr2 + br * NET;
    const float* wp = wn + (size_t)br * NET;
    int nb = br * NN;
    int beg = rp[d], end = rp[d + 1];
    const float4* Af = (const float4*)A;   // row = 8 float4
    float acc[8];
#pragma unroll
    for (int k = 0; k < 8; k++) acc[k] = 0.f;
    for (int j = beg; j < end; j += 4) {
        int i0 = j, i1 = j + 1, i2 = j + 2, i3 = j + 3;
        int c1 = i1 < end ? i1 : end - 1;
        int c2 = i2 < end ? i2 : end - 1;
        int c3 = i3 < end ? i3 : end - 1;
        float w0 = wp[i0];
        float w1 = i1 < end ? wp[c1] : 0.f;
        float w2 = i2 < end ? wp[c2] : 0.f;
        float w3 = i3 < end ? wp[c3] : 0.f;
        int s0 = nb + cs[i0];
        int s1 = nb + cs[c1];
        int s2 = nb + cs[c2];
        int s3 = nb + cs[c3];
        float4 f0 = Af[(size_t)s0 * 8 + li];
        float4 f1 = Af[(size_t)s1 * 8 + li];
        float4 f2 = Af[(size_t)s2 * 8 + li];
        float4 f3 = Af[(size_t)s3 * 8 + li];
        fma8(acc, f0, w0);
        fma8(acc, f1, w1);
        fma8(acc, f2, w2);
        fma8(acc, f3, w3);
    }
    const float4* bf = (const float4*)bias;
    float4 b0 = bf[2 * li], b1 = bf[2 * li + 1];
    __half2 o[4];
    o[0] = __floats2half2_rn(fast_tanh(acc[0] + b0.x), fast_tanh(acc[1] + b0.y));
    o[1] = __floats2half2_rn(fast_tanh(acc[2] + b0.z), fast_tanh(acc[3] + b0.w));
    o[2] = __floats2half2_rn(fast_tanh(acc[4] + b1.x), fast_tanh(acc[5] + b1.y));
    o[3] = __floats2half2_rn(fast_tanh(acc[6] + b1.z), fast_tanh(acc[7] + b1.w));
    ((float4*)B)[(size_t)dg * 8 + li] = *(float4*)o;
}

// GCN gather on pre-scaled Y, same 8-dst shape; mask via fma with 0/1.
__global__ __launch_bounds__(256) void k_gcn_gather8(
        const int* __restrict__ rowptr2, const u16* __restrict__ csr2,
        const float* __restrict__ dinv, const __half* __restrict__ Y,
        const float* __restrict__ bias, __half* __restrict__ Bout) {
    int lane = threadIdx.x & 63;
    int grp = lane >> 3, li = lane & 7;
    int dg = blockIdx.x * 32 + (threadIdx.x >> 6) * 8 + grp;
    int br = dg >= NN;
    int d = dg - br * NN;
    const int* rp = rowptr2 + br * (NN + 1);
    const u16* cs = csr2 + br * NET;
    int nb = br * NN;
    int beg = rp[d], end = rp[d + 1];
    const float4* Yf = (const float4*)Y;
    float acc[8];
#pragma unroll
    for (int k = 0; k < 8; k++) acc[k] = 0.f;
    for (int j = beg; j < end; j += 4) {
        int i1 = j + 1, i2 = j + 2, i3 = j + 3;
        int c1 = i1 < end ? i1 : end - 1;
        int c2 = i2 < end ? i2 : end - 1;
        int c3 = i3 < end ? i3 : end - 1;
        float w1 = i1 < end ? 1.f : 0.f;
        float w2 = i2 < end ? 1.f : 0.f;
        float w3 = i3 < end ? 1.f : 0.f;
        int s0 = nb + cs[j];
        int s1 = nb + cs[c1];
        int s2 = nb + cs[c2];
        int s3 = nb + cs[c3];
        float4 f0 = Yf[(size_t)s0 * 8 + li];
        float4 f1 = Yf[(size_t)s1 * 8 + li];
        float4 f2 = Yf[(size_t)s2 * 8 + li];
        float4 f3 = Yf[(size_t)s3 * 8 + li];
        fma8(acc, f0, 1.f);
        fma8(acc, f1, w1);
        fma8(acc, f2, w2);
        fma8(acc, f3, w3);
    }
    float dv = dinv[dg];
    const float4* bf = (const float4*)bias;
    float4 b0 = bf[2 * li], b1 = bf[2 * li + 1];
    __half2 o[4];
    o[0] = __floats2half2_rn(fast_tanh(acc[0] * dv + b0.x), fast_tanh(acc[1] * dv + b0.y));
    o[1] = __floats2half2_rn(fast_tanh(acc[2] * dv + b0.z), fast_tanh(acc[3] * dv + b0.w));
    o[2] = __floats2half2_rn(fast_tanh(acc[4] * dv + b1.x), fast_tanh(acc[5] * dv + b1.y));
    o[3] = __floats2half2_rn(fast_tanh(acc[6] * dv + b1.z), fast_tanh(acc[7] * dv + b1.w));
    ((float4*)Bout)[(size_t)dg * 8 + li] = *(float4*)o;
}

// Stage 64-node fp16 tile into LDS feature-major: sX[feat * NS + node].
__device__ __forceinline__ void load_tile_FM(const __half* __restrict__ X, int base,
                                             float* sX, int t) {
    const __half2* X2 = (const __half2*)X;
    for (int i = t; i < 2048; i += 256) {
        int node = i >> 5, p = i & 31;
        float2 v;
        if (base + node < 2 * NN) v = __half22float2(X2[(size_t)(base + node) * 32 + p]);
        else v = make_float2(0.f, 0.f);
        sX[(2 * p) * NS + node] = v.x;
        sX[(2 * p + 1) * NS + node] = v.y;
    }
}

// Dense Y = dinv[n] * (X @ W), 64-node tile, 4x4 blocking, fp16 weights/IO.
__global__ __launch_bounds__(256) void k_lin_tile(
        const __half* __restrict__ X, const float* __restrict__ W,
        const float* __restrict__ dinv, __half* __restrict__ Y) {
    __shared__ __half sW[64 * 64];
    __shared__ float sX[64 * NS];
    int t = threadIdx.x;
    for (int i = t; i < 4096; i += 256) sW[i] = __float2half(W[i]);
    int base = blockIdx.x * 64;
    load_tile_FM(X, base, sX, t);
    __syncthreads();
    int tx = t & 15, ty = t >> 4;
    float acc[4][4];
#pragma unroll
    for (int i = 0; i < 4; i++)
#pragma unroll
        for (int j = 0; j < 4; j++) acc[i][j] = 0.f;
#pragma unroll 4
    for (int k = 0; k < 64; k++) {
        uint2 wraw = *(const uint2*)&sW[k * 64 + 4 * tx];
        float2 wa = __half22float2(*(__half2*)&wraw.x);
        float2 wb = __half22float2(*(__half2*)&wraw.y);
        float4 xv = *(const float4*)&sX[k * NS + 4 * ty];
        acc[0][0] += xv.x * wa.x; acc[0][1] += xv.x * wa.y; acc[0][2] += xv.x * wb.x; acc[0][3] += xv.x * wb.y;
        acc[1][0] += xv.y * wa.x; acc[1][1] += xv.y * wa.y; acc[1][2] += xv.y * wb.x; acc[1][3] += xv.y * wb.y;
        acc[2][0] += xv.z * wa.x; acc[2][1] += xv.z * wa.y; acc[2][2] += xv.z * wb.x; acc[2][3] += xv.z * wb.y;
        acc[3][0] += xv.w * wa.x; acc[3][1] += xv.w * wa.y; acc[3][2] += xv.w * wb.x; acc[3][3] += xv.w * wb.y;
    }
#pragma unroll
    for (int i = 0; i < 4; i++) {
        int n = base + 4 * ty + i;
        if (n < 2 * NN) {
            float dv = dinv[n];
            __half2* Y2 = (__half2*)&Y[(size_t)n * 64 + 4 * tx];
            Y2[0] = __floats2half2_rn(acc[i][0] * dv, acc[i][1] * dv);
            Y2[1] = __floats2half2_rn(acc[i][2] * dv, acc[i][3] * dv);
        }
    }
}

// MLP (64->64 tanh ->32 tanh ->1) + mean-pool. Feature-major LDS, fp16 weights,
// segmented-run pool atomics.
__global__ __launch_bounds__(256) void k_mlp_pool(
        const __half* __restrict__ X,
        const int* __restrict__ batch_a, const int* __restrict__ batch_b,
        const float* __restrict__ W1, const float* __restrict__ b1,
        const float* __restrict__ W2, const float* __restrict__ b2,
        const float* __restrict__ W3, const float* __restrict__ b3,
        float* __restrict__ pool) {
    __shared__ __half sW1[64 * 64];
    __shared__ __half sW2[64 * 32];
    __shared__ float sX[64 * NS];
    __shared__ float sP[64 * 9];
    __shared__ float sW3[32], sb1[64], sb2[32];
    __shared__ int sKey[64];
    __shared__ float sVal[64];
    int t = threadIdx.x;
    for (int i = t; i < 4096; i += 256) sW1[i] = __float2half(W1[i]);
    for (int i = t; i < 2048; i += 256) sW2[i] = __float2half(W2[i]);
    if (t < 64) sb1[t] = b1[t];
    if (t < 32) { sW3[t] = W3[t]; sb2[t] = b2[t]; }
    float bb3 = b3[0];
    int base = blockIdx.x * 64;
    load_tile_FM(X, base, sX, t);
    __syncthreads();
    int tx = t & 15, ty = t >> 4;
    float acc[4][4];
#pragma unroll
    for (int i = 0; i < 4; i++)
#pragma unroll
        for (int j = 0; j < 4; j++) acc[i][j] = sb1[4 * tx + j];
#pragma unroll 4
    for (int k = 0; k < 64; k++) {
        uint2 wraw = *(const uint2*)&sW1[k * 64 + 4 * tx];
        float2 wa = __half22float2(*(__half2*)&wraw.x);
        float2 wb = __half22float2(*(__half2*)&wraw.y);
        float4 xv = *(const float4*)&sX[k * NS + 4 * ty];
        acc[0][0] += xv.x * wa.x; acc[0][1] += xv.x * wa.y; acc[0][2] += xv.x * wb.x; acc[0][3] += xv.x * wb.y;
        acc[1][0] += xv.y * wa.x; acc[1][1] += xv.y * wa.y; acc[1][2] += xv.y * wb.x; acc[1][3] += xv.y * wb.y;
        acc[2][0] += xv.z * wa.x; acc[2][1] += xv.z * wa.y; acc[2][2] += xv.z * wb.x; acc[2][3] += xv.z * wb.y;
        acc[3][0] += xv.w * wa.x; acc[3][1] += xv.w * wa.y; acc[3][2] += xv.w * wb.x; acc[3][3] += xv.w * wb.y;
    }
    __syncthreads();
#pragma unroll
    for (int j = 0; j < 4; j++) {
        float4 o = make_float4(fast_tanh(acc[0][j]), fast_tanh(acc[1][j]),
                               fast_tanh(acc[2][j]), fast_tanh(acc[3][j]));
        *(float4*)&sX[(4 * tx + j) * NS + 4 * ty] = o;
    }
    __syncthreads();
    int tx2 = t & 7, ty2 = t >> 3;
    float a2_[2][4];
#pragma unroll
    for (int i = 0; i < 2; i++)
#pragma unroll
        for (int j = 0; j < 4; j++) a2_[i][j] = sb2[4 * tx2 + j];
#pragma unroll 4
    for (int k = 0; k < 64; k++) {
        uint2 wraw = *(const uint2*)&sW2[k * 32 + 4 * tx2];
        float2 wa = __half22float2(*(__half2*)&wraw.x);
        float2 wb = __half22float2(*(__half2*)&wraw.y);
        float2 xv = *(const float2*)&sX[k * NS + 2 * ty2];
        a2_[0][0] += xv.x * wa.x; a2_[0][1] += xv.x * wa.y; a2_[0][2] += xv.x * wb.x; a2_[0][3] += xv.x * wb.y;
        a2_[1][0] += xv.y * wa.x; a2_[1][1] += xv.y * wa.y; a2_[1][2] += xv.y * wb.x; a2_[1][3] += xv.y * wb.y;
    }
#pragma unroll
    for (int i = 0; i < 2; i++) {
        float p = fast_tanh(a2_[i][0]) * sW3[4 * tx2]
                + fast_tanh(a2_[i][1]) * sW3[4 * tx2 + 1]
                + fast_tanh(a2_[i][2]) * sW3[4 * tx2 + 2]
                + fast_tanh(a2_[i][3]) * sW3[4 * tx2 + 3];
        sP[(2 * ty2 + i) * 9 + tx2] = p;
    }
    __syncthreads();
    if (t < 64) {
        int n = base + t;
        bool valid = n < 2 * NN;
        int br = n >= NN;
        int g = valid ? (br ? batch_b[n - NN] : batch_a[n]) : -1;
        int key = valid ? (br * 4096 + g) : -1;
        float s0 = sP[t * 9 + 0] + sP[t * 9 + 1] + sP[t * 9 + 2] + sP[t * 9 + 3];
        float s1 = sP[t * 9 + 4] + sP[t * 9 + 5] + sP[t * 9 + 6] + sP[t * 9 + 7];
        sKey[t] = key;
        sVal[t] = s0 + s1 + bb3;
        if (valid && (t == 0 || sKey[t - 1] != key)) {
            float sum = 0.f;
            int cnt = 0;
            for (int j = t; j < 64 && sKey[j] == key; j++) { sum += sVal[j]; cnt++; }
            float* bin = pool + br * 2 * NG;
            atomicAdd(&bin[g], sum);
            atomicAdd(&bin[NG + g], (float)cnt);
        }
    }
}

// pool layout: [sa(NG), ca(NG), sb(NG), cb(NG)]
__global__ void k_final(const float* __restrict__ pool, float* __restrict__ out) {
    int g = blockIdx.x * 256 + threadIdx.x;
    if (g >= NG) return;
    float ua = pool[g] / fmaxf(pool[NG + g], 1.f);
    float ub = pool[2 * NG + g] / fmaxf(pool[3 * NG + g], 1.f);
    float z = ub - ua;
    out[g] = 1.f / (1.f + __expf(-z));
}

extern "C" void kernel_launch(void* const* d_in, const int* in_sizes, int n_in,
                              void* d_out, int out_size, void* d_ws, size_t ws_size,
                              hipStream_t stream) {
    const float* x_a = (const float*)d_in[0];
    const float* x_b = (const float*)d_in[1];
    const int* ei_a = (const int*)d_in[2];
    const int* ei_b = (const int*)d_in[3];
    const int* batch_a = (const int*)d_in[4];
    const int* batch_b = (const int*)d_in[5];
    const float* Wg   = (const float*)d_in[6];
    const float* avs  = (const float*)d_in[7];
    const float* avd  = (const float*)d_in[8];
    const float* bg   = (const float*)d_in[9];
    const float* Wgcn = (const float*)d_in[10];
    const float* bgcn = (const float*)d_in[11];
    const float* W1 = (const float*)d_in[12];
    const float* b1 = (const float*)d_in[13];
    const float* W2 = (const float*)d_in[14];
    const float* b2 = (const float*)d_in[15];
    const float* W3 = (const float*)d_in[16];
    const float* b3 = (const float*)d_in[17];

    char* w = (char*)d_ws;
    __half* A2 = (__half*)w;          w += (size_t)2 * NN * 64 * 2;   // 12.8 MB
    __half* B2 = (__half*)w;          w += (size_t)2 * NN * 64 * 2;   // 12.8 MB
    float* als2 = (float*)w;          w += (size_t)2 * NN * 4;
    float* ald2 = (float*)w;          w += (size_t)2 * NN * 4;
    float* dinv2 = (float*)w;         w += (size_t)2 * NN * 4;
    float* pool = (float*)w;          w += (size_t)4 * NG * 4;
    int* rowptr2 = (int*)w;           w += (size_t)2 * (NN + 1) * 4;
    int* cnts = (int*)w;              w += (size_t)2 * NSL * NCK * 4; // 163 KB
    int* sliceBase = (int*)w;         w += (size_t)2 * (NSL + 1) * 4;
    u16* csr2 = (u16*)w;              w += (size_t)2 * NET * 2;       // 3.4 MB
    float* wn = (float*)w;            w += (size_t)2 * NET * 4;       // 6.8 MB
    // staging (2*NET u32 = 6.8 MB) aliases A2: dead before k_gat_input writes A2
    unsigned int* staging = (unsigned int*)A2;

    dim3 blk(256);

    // CSR build: atomic-free bucket sort
    k_hist<<<2 * NCK, blk, 0, stream>>>(ei_a, ei_b, cnts);
    k_off1<<<2 * NSL, dim3(64), 0, stream>>>(cnts, sliceBase);
    k_off2<<<1, blk, 0, stream>>>(sliceBase, rowptr2, pool);
    k_bucket<<<2 * NCK, blk, 0, stream>>>(ei_a, ei_b, cnts, sliceBase, staging);
    k_slice<<<2 * NSL, dim3(512), 0, stream>>>(staging, sliceBase, rowptr2, dinv2, csr2);

    k_gat_input<<<GN4, blk, 0, stream>>>(x_a, x_b, Wg, avs, avd, A2, als2, ald2);
    k_edgew<<<GN8, blk, 0, stream>>>(rowptr2, csr2, als2, ald2, wn);
    k_gat_gather8<<<GN32, blk, 0, stream>>>(rowptr2, csr2, wn, A2, bg, B2);
    k_lin_tile<<<NT2, blk, 0, stream>>>(B2, Wgcn, dinv2, A2);
    k_gcn_gather8<<<GN32, blk, 0, stream>>>(rowptr2, csr2, dinv2, A2, bgcn, B2);
    k_lin_tile<<<NT2, blk, 0, stream>>>(B2, Wgcn + 64 * 64, dinv2, A2);
    k_gcn_gather8<<<GN32, blk, 0, stream>>>(rowptr2, csr2, dinv2, A2, bgcn + 64, B2);
    k_mlp_pool<<<NT2, blk, 0, stream>>>(B2, batch_a, batch_b, W1, b1, W2, b2, W3, b3, pool);

    k_final<<<(NG + 255) / 256, blk, 0, stream>>>(pool, (float*)d_out);
}

// Round 3
// 354.561 us; speedup vs baseline: 1.0960x; 1.0016x over previous
//
#include <hip/hip_runtime.h>
#include <hip/hip_fp16.h>
#include <math.h>

#define NN 50000
#define NE 800000
#define NG 512
#define NET (NE + NN)            // edges + self loops
#define NT2 ((2 * NN + 63) / 64) // 1563 64-node tiles over both branches
#define GN4 ((2 * NN + 3) / 4)   // wave-per-node grids
#define GN8 ((2 * NN + 7) / 8)   // 2-dst-per-wave grids
#define GN32 ((2 * NN + 31) / 32) // 8-dst-per-wave gather grids (3125, exact)
#define NSH 68                   // feature-major LDS stride (halfs)

// bucket-sort CSR build
#define SLICE 512                        // dst nodes per slice
#define NSL ((NN + SLICE - 1) / SLICE)   // 98 slices per branch
#define CHK 4096                         // edges per chunk
#define NCK ((NET + CHK - 1) / CHK)      // 208 chunks per branch
#define CAP 10240                        // LDS csr buffer per slice

typedef unsigned short u16;

__device__ __forceinline__ float wsum64(float v) {
#pragma unroll
    for (int o = 32; o > 0; o >>= 1) v += __shfl_down(v, o, 64);
    return v;
}

__device__ __forceinline__ float fast_tanh(float x) {
    return 1.f - 2.f / (__expf(2.f * x) + 1.f);
}

// ---------------- CSR build: atomic-free two-level bucket sort ----------------

__global__ __launch_bounds__(256) void k_hist(const int* __restrict__ eia,
                                              const int* __restrict__ eib,
                                              int* __restrict__ cnts) {
    __shared__ int h[NSL];
    int b = blockIdx.x;
    int br = b >= NCK, c = b - (br ? NCK : 0);
    int t = threadIdx.x;
    for (int i = t; i < NSL; i += 256) h[i] = 0;
    __syncthreads();
    const int* ei = br ? eib : eia;
    int e0 = c * CHK, e1 = e0 + CHK; if (e1 > NET) e1 = NET;
    for (int e = e0 + t; e < e1; e += 256) {
        int d = (e < NE) ? __builtin_nontemporal_load(&ei[NE + e]) : (e - NE);
        atomicAdd(&h[d >> 9], 1);
    }
    __syncthreads();
    for (int i = t; i < NSL; i += 256) cnts[(br * NSL + i) * NCK + c] = h[i];
}

__global__ __launch_bounds__(64) void k_off1(int* __restrict__ cnts,
                                             int* __restrict__ sliceBase) {
    int b = blockIdx.x;                  // 2*NSL
    int br = b >= NSL, s = b - (br ? NSL : 0);
    int lane = threadIdx.x;
    int* row = cnts + (br * NSL + s) * NCK;
    int run = 0;
    for (int c0 = 0; c0 < NCK; c0 += 64) {
        int c = c0 + lane;
        int v = (c < NCK) ? row[c] : 0;
        int orig = v;
#pragma unroll
        for (int o = 1; o < 64; o <<= 1) {
            int tv = __shfl_up(v, o, 64);
            if (lane >= o) v += tv;
        }
        if (c < NCK) row[c] = run + v - orig;
        run += __shfl(v, 63, 64);
    }
    if (lane == 0) sliceBase[br * (NSL + 1) + s] = run;
}

__global__ void k_off2(int* __restrict__ sliceBase, int* __restrict__ rowptr2,
                       float* __restrict__ pool) {
    int t = threadIdx.x;  // 256
    for (int i = t; i < 4 * NG; i += 256) pool[i] = 0.f;
    if (t < 2) {
        int* sb = sliceBase + t * (NSL + 1);
        int run = 0;
        for (int s = 0; s < NSL; s++) { int v = sb[s]; sb[s] = run; run += v; }
        sb[NSL] = run;
        rowptr2[t * (NN + 1) + NN] = run;
    }
}

__global__ __launch_bounds__(256) void k_bucket(const int* __restrict__ eia,
                                                const int* __restrict__ eib,
                                                const int* __restrict__ cnts,
                                                const int* __restrict__ sliceBase,
                                                unsigned int* __restrict__ staging) {
    __shared__ int cur[NSL];
    int b = blockIdx.x;
    int br = b >= NCK, c = b - (br ? NCK : 0);
    int t = threadIdx.x;
    for (int i = t; i < NSL; i += 256)
        cur[i] = cnts[(br * NSL + i) * NCK + c] + sliceBase[br * (NSL + 1) + i];
    __syncthreads();
    const int* ei = br ? eib : eia;
    unsigned int* stg = staging + (size_t)br * NET;
    int e0 = c * CHK, e1 = e0 + CHK; if (e1 > NET) e1 = NET;
    for (int e = e0 + t; e < e1; e += 256) {
        int d, s;
        if (e < NE) {
            d = __builtin_nontemporal_load(&ei[NE + e]);
            s = __builtin_nontemporal_load(&ei[e]);
        } else { d = e - NE; s = d; }
        int pos = atomicAdd(&cur[d >> 9], 1);   // LDS atomic
        stg[pos] = ((unsigned int)(d & 511) << 16) | (unsigned int)s;
    }
}

__global__ __launch_bounds__(512) void k_slice(const unsigned int* __restrict__ staging,
                                               const int* __restrict__ sliceBase,
                                               int* __restrict__ rowptr2,
                                               float* __restrict__ dinv2,
                                               u16* __restrict__ csr2) {
    __shared__ int sc[512];
    __shared__ int cur[512];
    __shared__ u16 buf[CAP];
    int b = blockIdx.x;
    int br = b >= NSL, sl = b - (br ? NSL : 0);
    int t = threadIdx.x;
    const int* sb = sliceBase + br * (NSL + 1);
    int base = sb[sl], m = sb[sl + 1] - base;
    const unsigned int* st = staging + (size_t)br * NET + base;
    cur[t] = 0;
    __syncthreads();
    for (int i = t; i < m; i += 512) atomicAdd(&cur[st[i] >> 16], 1);
    __syncthreads();
    int v = cur[t];
    sc[t] = v;
    __syncthreads();
    for (int o = 1; o < 512; o <<= 1) {
        int add = (t >= o) ? sc[t - o] : 0;
        __syncthreads();
        sc[t] += add;
        __syncthreads();
    }
    int excl = sc[t] - v;
    int node = sl * SLICE + t;
    if (node < NN) {
        rowptr2[br * (NN + 1) + node] = base + excl;
        dinv2[br * NN + node] = v > 0 ? rsqrtf((float)v) : 0.f;
    }
    cur[t] = excl;
    __syncthreads();
    for (int i = t; i < m; i += 512) {
        unsigned int e = st[i];
        int pos = atomicAdd(&cur[e >> 16], 1);
        if (pos < CAP) buf[pos] = (u16)(e & 0xffffu);
    }
    __syncthreads();
    u16* out = csr2 + (size_t)br * NET + base;
    int mm = m < CAP ? m : CAP;
    for (int i = t; i < mm; i += 512) out[i] = buf[i];
}

// fp16 weight cache: [W1h(4096) | W2h(2048) | Wg0h(4096) | Wg1h(4096)]
__global__ __launch_bounds__(256) void k_wprep(const float* __restrict__ W1,
                                               const float* __restrict__ W2,
                                               const float* __restrict__ Wgcn,
                                               __half* __restrict__ out) {
    int i = blockIdx.x * 256 + threadIdx.x;  // 56 blocks * 256 = 14336
    float v;
    if (i < 4096) v = W1[i];
    else if (i < 6144) v = W2[i - 4096];
    else v = Wgcn[i - 6144];
    out[i] = __float2half(v);
}

// ---------------- node-level kernels (node id in [0,2*NN)) ----

__global__ void k_gat_input(const float* __restrict__ xa, const float* __restrict__ xb,
                            const float* __restrict__ Wg,
                            const float* __restrict__ avs, const float* __restrict__ avd,
                            __half* __restrict__ A, float* __restrict__ als,
                            float* __restrict__ ald) {
    __shared__ float sW[9 * 64];
    __shared__ float sas[64], sad[64];
    int t = threadIdx.x;
    for (int i = t; i < 9 * 64; i += 256) sW[i] = Wg[i];
    if (t < 64) { sas[t] = avs[t]; sad[t] = avd[t]; }
    __syncthreads();
    int n = blockIdx.x * 4 + (t >> 6);
    int u = t & 63;
    if (n >= 2 * NN) return;
    const float* xp = (n < NN) ? &xa[(size_t)n * 9] : &xb[(size_t)(n - NN) * 9];
    float h = 0.f;
#pragma unroll
    for (int f = 0; f < 9; f++) h += xp[f] * sW[f * 64 + u];
    A[(size_t)n * 64 + u] = __float2half(h);
    float ps = wsum64(h * sas[u]);
    float pd = wsum64(h * sad[u]);
    if (u == 0) { als[n] = ps; ald[n] = pd; }
}

// Normalized edge weights, CSR order: wn[j] = exp(lrelu(als[src]+ald[dst]))/den.
// Half-wave per dst, lane-parallel over edges (1 exp/edge). No max-stab
// (|e|<~25, fp32-safe).
__global__ __launch_bounds__(256) void k_edgew(
        const int* __restrict__ rowptr2, const u16* __restrict__ csr2,
        const float* __restrict__ als, const float* __restrict__ ald,
        float* __restrict__ wn) {
    int u = threadIdx.x & 63;
    int lu = u & 31;
    int dg = blockIdx.x * 8 + (threadIdx.x >> 6) * 2 + (u >> 5);
    if (dg >= 2 * NN) return;
    int br = dg >= NN;
    int d = dg - br * NN;
    const int* rp = rowptr2 + br * (NN + 1);
    const u16* cs = csr2 + br * NET;
    float* wp = wn + (size_t)br * NET;
    int nb = br * NN;
    int beg = rp[d], end = rp[d + 1];
    float ad = ald[dg];
    float den = 0.f;
    for (int c = beg + lu; c < end; c += 32) {
        int s = nb + cs[c];
        float v = als[s] + ad;
        float w = __expf(fmaxf(v, 0.2f * v));
        den += w;
        wp[c] = w;
    }
#pragma unroll
    for (int o = 16; o > 0; o >>= 1) den += __shfl_down(den, o, 32);
    den = __shfl(den, 0, 32);
    float inv = 1.f / den;
    for (int c = beg + lu; c < end; c += 32) wp[c] *= inv;
}

// 8 halfs of a feature row, weighted-accumulated into 8 f32.
__device__ __forceinline__ void fma8(float* acc, float4 f, float w) {
    const __half2* h = (const __half2*)&f;
#pragma unroll
    for (int p = 0; p < 4; p++) {
        float2 v = __half22float2(h[p]);
        acc[2 * p]     += v.x * w;
        acc[2 * p + 1] += v.y * w;
    }
}

// GAT gather with precomputed normalized weights. 8 dsts per wave.
__global__ __launch_bounds__(256) void k_gat_gather8(
        const int* __restrict__ rowptr2, const u16* __restrict__ csr2,
        const float* __restrict__ wn, const __half* __restrict__ A,
        const float* __restrict__ bias, __half* __restrict__ B) {
    int lane = threadIdx.x & 63;
    int grp = lane >> 3, li = lane & 7;
    int dg = blockIdx.x * 32 + (threadIdx.x >> 6) * 8 + grp;  // grid exact: 3125*32=100000
    int br = dg >= NN;
    int d = dg - br * NN;
    const int* rp = rowptr2 + br * (NN + 1);
    const u16* cs = csr2 + br * NET;
    const float* wp = wn + (size_t)br * NET;
    int nb = br * NN;
    int beg = rp[d], end = rp[d + 1];
    const float4* Af = (const float4*)A;   // row = 8 float4
    float acc[8];
#pragma unroll
    for (int k = 0; k < 8; k++) acc[k] = 0.f;
    for (int j = beg; j < end; j += 4) {
        int i0 = j, i1 = j + 1, i2 = j + 2, i3 = j + 3;
        int c1 = i1 < end ? i1 : end - 1;
        int c2 = i2 < end ? i2 : end - 1;
        int c3 = i3 < end ? i3 : end - 1;
        float w0 = wp[i0];
        float w1 = i1 < end ? wp[c1] : 0.f;
        float w2 = i2 < end ? wp[c2] : 0.f;
        float w3 = i3 < end ? wp[c3] : 0.f;
        int s0 = nb + cs[i0];
        int s1 = nb + cs[c1];
        int s2 = nb + cs[c2];
        int s3 = nb + cs[c3];
        float4 f0 = Af[(size_t)s0 * 8 + li];
        float4 f1 = Af[(size_t)s1 * 8 + li];
        float4 f2 = Af[(size_t)s2 * 8 + li];
        float4 f3 = Af[(size_t)s3 * 8 + li];
        fma8(acc, f0, w0);
        fma8(acc, f1, w1);
        fma8(acc, f2, w2);
        fma8(acc, f3, w3);
    }
    const float4* bf = (const float4*)bias;
    float4 b0 = bf[2 * li], b1 = bf[2 * li + 1];
    __half2 o[4];
    o[0] = __floats2half2_rn(fast_tanh(acc[0] + b0.x), fast_tanh(acc[1] + b0.y));
    o[1] = __floats2half2_rn(fast_tanh(acc[2] + b0.z), fast_tanh(acc[3] + b0.w));
    o[2] = __floats2half2_rn(fast_tanh(acc[4] + b1.x), fast_tanh(acc[5] + b1.y));
    o[3] = __floats2half2_rn(fast_tanh(acc[6] + b1.z), fast_tanh(acc[7] + b1.w));
    ((float4*)B)[(size_t)dg * 8 + li] = *(float4*)o;
}

// GCN gather on pre-scaled Y, same 8-dst shape; mask via fma with 0/1.
__global__ __launch_bounds__(256) void k_gcn_gather8(
        const int* __restrict__ rowptr2, const u16* __restrict__ csr2,
        const float* __restrict__ dinv, const __half* __restrict__ Y,
        const float* __restrict__ bias, __half* __restrict__ Bout) {
    int lane = threadIdx.x & 63;
    int grp = lane >> 3, li = lane & 7;
    int dg = blockIdx.x * 32 + (threadIdx.x >> 6) * 8 + grp;
    int br = dg >= NN;
    int d = dg - br * NN;
    const int* rp = rowptr2 + br * (NN + 1);
    const u16* cs = csr2 + br * NET;
    int nb = br * NN;
    int beg = rp[d], end = rp[d + 1];
    const float4* Yf = (const float4*)Y;
    float acc[8];
#pragma unroll
    for (int k = 0; k < 8; k++) acc[k] = 0.f;
    for (int j = beg; j < end; j += 4) {
        int i1 = j + 1, i2 = j + 2, i3 = j + 3;
        int c1 = i1 < end ? i1 : end - 1;
        int c2 = i2 < end ? i2 : end - 1;
        int c3 = i3 < end ? i3 : end - 1;
        float w1 = i1 < end ? 1.f : 0.f;
        float w2 = i2 < end ? 1.f : 0.f;
        float w3 = i3 < end ? 1.f : 0.f;
        int s0 = nb + cs[j];
        int s1 = nb + cs[c1];
        int s2 = nb + cs[c2];
        int s3 = nb + cs[c3];
        float4 f0 = Yf[(size_t)s0 * 8 + li];
        float4 f1 = Yf[(size_t)s1 * 8 + li];
        float4 f2 = Yf[(size_t)s2 * 8 + li];
        float4 f3 = Yf[(size_t)s3 * 8 + li];
        fma8(acc, f0, 1.f);
        fma8(acc, f1, w1);
        fma8(acc, f2, w2);
        fma8(acc, f3, w3);
    }
    float dv = dinv[dg];
    const float4* bf = (const float4*)bias;
    float4 b0 = bf[2 * li], b1 = bf[2 * li + 1];
    __half2 o[4];
    o[0] = __floats2half2_rn(fast_tanh(acc[0] * dv + b0.x), fast_tanh(acc[1] * dv + b0.y));
    o[1] = __floats2half2_rn(fast_tanh(acc[2] * dv + b0.z), fast_tanh(acc[3] * dv + b0.w));
    o[2] = __floats2half2_rn(fast_tanh(acc[4] * dv + b1.x), fast_tanh(acc[5] * dv + b1.y));
    o[3] = __floats2half2_rn(fast_tanh(acc[6] * dv + b1.z), fast_tanh(acc[7] * dv + b1.w));
    ((float4*)Bout)[(size_t)dg * 8 + li] = *(float4*)o;
}

// Stage 64-node fp16 tile into LDS feature-major fp16: sXh[feat * NSH + node].
// float4 global loads (8 halfs = 1 node x 8 feats), u16 LDS scatter.
__device__ __forceinline__ void load_tile_FM16(const __half* __restrict__ X, int base,
                                               __half* sXh, int t) {
    const float4* Xf = (const float4*)X;
#pragma unroll
    for (int rep = 0; rep < 2; rep++) {
        int i = t + rep * 256;           // 512 float4s = 64 nodes x 8
        int node = i >> 3, q = i & 7;
        float4 raw;
        if (base + node < 2 * NN) raw = Xf[(size_t)(base + node) * 8 + q];
        else raw = make_float4(0.f, 0.f, 0.f, 0.f);
        const __half* hv = (const __half*)&raw;
#pragma unroll
        for (int e = 0; e < 8; e++) sXh[(8 * q + e) * NSH + node] = hv[e];
    }
}

// Dense Y = dinv[n] * (X @ W), 64-node tile, 4x4 blocking, fp16 weights/LDS/IO.
// LDS ~16.9 KB -> 8 blocks/CU occupancy cap.
__global__ __launch_bounds__(256) void k_lin_tile(
        const __half* __restrict__ X, const __half* __restrict__ Wh,
        const float* __restrict__ dinv, __half* __restrict__ Y) {
    __shared__ __half sW[64 * 64];
    __shared__ __half sXh[64 * NSH];
    int t = threadIdx.x;
    {
        const uint4* src = (const uint4*)Wh;
        uint4* dst = (uint4*)sW;
        for (int i = t; i < 512; i += 256) dst[i] = src[i];
    }
    int base = blockIdx.x * 64;
    load_tile_FM16(X, base, sXh, t);
    __syncthreads();
    int tx = t & 15, ty = t >> 4;
    float acc[4][4];
#pragma unroll
    for (int i = 0; i < 4; i++)
#pragma unroll
        for (int j = 0; j < 4; j++) acc[i][j] = 0.f;
#pragma unroll 4
    for (int k = 0; k < 64; k++) {
        uint2 wraw = *(const uint2*)&sW[k * 64 + 4 * tx];
        float2 wa = __half22float2(*(__half2*)&wraw.x);
        float2 wb = __half22float2(*(__half2*)&wraw.y);
        uint2 xraw = *(const uint2*)&sXh[k * NSH + 4 * ty];
        float2 xa = __half22float2(*(__half2*)&xraw.x);
        float2 xb = __half22float2(*(__half2*)&xraw.y);
        acc[0][0] += xa.x * wa.x; acc[0][1] += xa.x * wa.y; acc[0][2] += xa.x * wb.x; acc[0][3] += xa.x * wb.y;
        acc[1][0] += xa.y * wa.x; acc[1][1] += xa.y * wa.y; acc[1][2] += xa.y * wb.x; acc[1][3] += xa.y * wb.y;
        acc[2][0] += xb.x * wa.x; acc[2][1] += xb.x * wa.y; acc[2][2] += xb.x * wb.x; acc[2][3] += xb.x * wb.y;
        acc[3][0] += xb.y * wa.x; acc[3][1] += xb.y * wa.y; acc[3][2] += xb.y * wb.x; acc[3][3] += xb.y * wb.y;
    }
#pragma unroll
    for (int i = 0; i < 4; i++) {
        int n = base + 4 * ty + i;
        if (n < 2 * NN) {
            float dv = dinv[n];
            __half2* Y2 = (__half2*)&Y[(size_t)n * 64 + 4 * tx];
            Y2[0] = __floats2half2_rn(acc[i][0] * dv, acc[i][1] * dv);
            Y2[1] = __floats2half2_rn(acc[i][2] * dv, acc[i][3] * dv);
        }
    }
}

// MLP (64->64 tanh ->32 tanh ->1) + mean-pool. fp16 weights/LDS.
// LDS ~24 KB -> 6 blocks/CU occupancy cap (was 4).
__global__ __launch_bounds__(256) void k_mlp_pool(
        const __half* __restrict__ X,
        const int* __restrict__ batch_a, const int* __restrict__ batch_b,
        const __half* __restrict__ W1h, const float* __restrict__ b1,
        const __half* __restrict__ W2h, const float* __restrict__ b2,
        const float* __restrict__ W3, const float* __restrict__ b3,
        float* __restrict__ pool) {
    __shared__ __half sW1[64 * 64];
    __shared__ __half sW2[64 * 32];
    __shared__ __half sXh[64 * NSH];
    __shared__ float sP[64 * 9];
    __shared__ float sW3[32], sb1[64], sb2[32];
    __shared__ int sKey[64];
    __shared__ float sVal[64];
    int t = threadIdx.x;
    {
        const uint4* s1 = (const uint4*)W1h;
        uint4* d1 = (uint4*)sW1;
        for (int i = t; i < 512; i += 256) d1[i] = s1[i];
        const uint4* s2 = (const uint4*)W2h;
        uint4* d2 = (uint4*)sW2;
        if (t < 256) d2[t] = s2[t];
    }
    if (t < 64) sb1[t] = b1[t];
    if (t < 32) { sW3[t] = W3[t]; sb2[t] = b2[t]; }
    float bb3 = b3[0];
    int base = blockIdx.x * 64;
    load_tile_FM16(X, base, sXh, t);
    __syncthreads();
    int tx = t & 15, ty = t >> 4;
    float acc[4][4];
#pragma unroll
    for (int i = 0; i < 4; i++)
#pragma unroll
        for (int j = 0; j < 4; j++) acc[i][j] = sb1[4 * tx + j];
#pragma unroll 4
    for (int k = 0; k < 64; k++) {
        uint2 wraw = *(const uint2*)&sW1[k * 64 + 4 * tx];
        float2 wa = __half22float2(*(__half2*)&wraw.x);
        float2 wb = __half22float2(*(__half2*)&wraw.y);
        uint2 xraw = *(const uint2*)&sXh[k * NSH + 4 * ty];
        float2 xa = __half22float2(*(__half2*)&xraw.x);
        float2 xb = __half22float2(*(__half2*)&xraw.y);
        acc[0][0] += xa.x * wa.x; acc[0][1] += xa.x * wa.y; acc[0][2] += xa.x * wb.x; acc[0][3] += xa.x * wb.y;
        acc[1][0] += xa.y * wa.x; acc[1][1] += xa.y * wa.y; acc[1][2] += xa.y * wb.x; acc[1][3] += xa.y * wb.y;
        acc[2][0] += xb.x * wa.x; acc[2][1] += xb.x * wa.y; acc[2][2] += xb.x * wb.x; acc[2][3] += xb.x * wb.y;
        acc[3][0] += xb.y * wa.x; acc[3][1] += xb.y * wa.y; acc[3][2] += xb.y * wb.x; acc[3][3] += xb.y * wb.y;
    }
    __syncthreads();
    // tanh intermediate back to sXh feature-major: feat 4*tx+j, nodes 4*ty..4*ty+3
#pragma unroll
    for (int j = 0; j < 4; j++) {
        __half2 h01 = __floats2half2_rn(fast_tanh(acc[0][j]), fast_tanh(acc[1][j]));
        __half2 h23 = __floats2half2_rn(fast_tanh(acc[2][j]), fast_tanh(acc[3][j]));
        uint2 packed = make_uint2(*(unsigned int*)&h01, *(unsigned int*)&h23);
        *(uint2*)&sXh[(4 * tx + j) * NSH + 4 * ty] = packed;
    }
    __syncthreads();
    int tx2 = t & 7, ty2 = t >> 3;
    float a2_[2][4];
#pragma unroll
    for (int i = 0; i < 2; i++)
#pragma unroll
        for (int j = 0; j < 4; j++) a2_[i][j] = sb2[4 * tx2 + j];
#pragma unroll 4
    for (int k = 0; k < 64; k++) {
        uint2 wraw = *(const uint2*)&sW2[k * 32 + 4 * tx2];
        float2 wa = __half22float2(*(__half2*)&wraw.x);
        float2 wb = __half22float2(*(__half2*)&wraw.y);
        unsigned int xraw = *(const unsigned int*)&sXh[k * NSH + 2 * ty2];
        float2 xv = __half22float2(*(__half2*)&xraw);
        a2_[0][0] += xv.x * wa.x; a2_[0][1] += xv.x * wa.y; a2_[0][2] += xv.x * wb.x; a2_[0][3] += xv.x * wb.y;
        a2_[1][0] += xv.y * wa.x; a2_[1][1] += xv.y * wa.y; a2_[1][2] += xv.y * wb.x; a2_[1][3] += xv.y * wb.y;
    }
#pragma unroll
    for (int i = 0; i < 2; i++) {
        float p = fast_tanh(a2_[i][0]) * sW3[4 * tx2]
                + fast_tanh(a2_[i][1]) * sW3[4 * tx2 + 1]
                + fast_tanh(a2_[i][2]) * sW3[4 * tx2 + 2]
                + fast_tanh(a2_[i][3]) * sW3[4 * tx2 + 3];
        sP[(2 * ty2 + i) * 9 + tx2] = p;
    }
    __syncthreads();
    if (t < 64) {
        int n = base + t;
        bool valid = n < 2 * NN;
        int br = n >= NN;
        int g = valid ? (br ? batch_b[n - NN] : batch_a[n]) : -1;
        int key = valid ? (br * 4096 + g) : -1;
        float s0 = sP[t * 9 + 0] + sP[t * 9 + 1] + sP[t * 9 + 2] + sP[t * 9 + 3];
        float s1 = sP[t * 9 + 4] + sP[t * 9 + 5] + sP[t * 9 + 6] + sP[t * 9 + 7];
        sKey[t] = key;
        sVal[t] = s0 + s1 + bb3;
        if (valid && (t == 0 || sKey[t - 1] != key)) {
            float sum = 0.f;
            int cnt = 0;
            for (int j = t; j < 64 && sKey[j] == key; j++) { sum += sVal[j]; cnt++; }
            float* bin = pool + br * 2 * NG;
            atomicAdd(&bin[g], sum);
            atomicAdd(&bin[NG + g], (float)cnt);
        }
    }
}

// pool layout: [sa(NG), ca(NG), sb(NG), cb(NG)]
__global__ void k_final(const float* __restrict__ pool, float* __restrict__ out) {
    int g = blockIdx.x * 256 + threadIdx.x;
    if (g >= NG) return;
    float ua = pool[g] / fmaxf(pool[NG + g], 1.f);
    float ub = pool[2 * NG + g] / fmaxf(pool[3 * NG + g], 1.f);
    float z = ub - ua;
    out[g] = 1.f / (1.f + __expf(-z));
}

extern "C" void kernel_launch(void* const* d_in, const int* in_sizes, int n_in,
                              void* d_out, int out_size, void* d_ws, size_t ws_size,
                              hipStream_t stream) {
    const float* x_a = (const float*)d_in[0];
    const float* x_b = (const float*)d_in[1];
    const int* ei_a = (const int*)d_in[2];
    const int* ei_b = (const int*)d_in[3];
    const int* batch_a = (const int*)d_in[4];
    const int* batch_b = (const int*)d_in[5];
    const float* Wg   = (const float*)d_in[6];
    const float* avs  = (const float*)d_in[7];
    const float* avd  = (const float*)d_in[8];
    const float* bg   = (const float*)d_in[9];
    const float* Wgcn = (const float*)d_in[10];
    const float* bgcn = (const float*)d_in[11];
    const float* W1 = (const float*)d_in[12];
    const float* b1 = (const float*)d_in[13];
    const float* W2 = (const float*)d_in[14];
    const float* b2 = (const float*)d_in[15];
    const float* W3 = (const float*)d_in[16];
    const float* b3 = (const float*)d_in[17];

    char* w = (char*)d_ws;
    __half* A2 = (__half*)w;          w += (size_t)2 * NN * 64 * 2;   // 12.8 MB
    __half* B2 = (__half*)w;          w += (size_t)2 * NN * 64 * 2;   // 12.8 MB
    float* als2 = (float*)w;          w += (size_t)2 * NN * 4;
    float* ald2 = (float*)w;          w += (size_t)2 * NN * 4;
    float* dinv2 = (float*)w;         w += (size_t)2 * NN * 4;
    float* pool = (float*)w;          w += (size_t)4 * NG * 4;
    int* rowptr2 = (int*)w;           w += (size_t)2 * (NN + 1) * 4;
    int* cnts = (int*)w;              w += (size_t)2 * NSL * NCK * 4; // 163 KB
    int* sliceBase = (int*)w;         w += (size_t)2 * (NSL + 1) * 4;
    u16* csr2 = (u16*)w;              w += (size_t)2 * NET * 2;       // 3.4 MB
    float* wn = (float*)w;            w += (size_t)2 * NET * 4;       // 6.8 MB
    __half* wcache = (__half*)w;      w += (size_t)14336 * 2;         // 28 KB
    // staging (2*NET u32 = 6.8 MB) aliases A2: dead before k_gat_input writes A2
    unsigned int* staging = (unsigned int*)A2;

    __half* W1h = wcache;
    __half* W2h = wcache + 4096;
    __half* Wg0h = wcache + 6144;
    __half* Wg1h = wcache + 10240;

    dim3 blk(256);

    // CSR build: atomic-free bucket sort
    k_hist<<<2 * NCK, blk, 0, stream>>>(ei_a, ei_b, cnts);
    k_wprep<<<56, blk, 0, stream>>>(W1, W2, Wgcn, wcache);
    k_off1<<<2 * NSL, dim3(64), 0, stream>>>(cnts, sliceBase);
    k_off2<<<1, blk, 0, stream>>>(sliceBase, rowptr2, pool);
    k_bucket<<<2 * NCK, blk, 0, stream>>>(ei_a, ei_b, cnts, sliceBase, staging);
    k_slice<<<2 * NSL, dim3(512), 0, stream>>>(staging, sliceBase, rowptr2, dinv2, csr2);

    k_gat_input<<<GN4, blk, 0, stream>>>(x_a, x_b, Wg, avs, avd, A2, als2, ald2);
    k_edgew<<<GN8, blk, 0, stream>>>(rowptr2, csr2, als2, ald2, wn);
    k_gat_gather8<<<GN32, blk, 0, stream>>>(rowptr2, csr2, wn, A2, bg, B2);
    k_lin_tile<<<NT2, blk, 0, stream>>>(B2, Wg0h, dinv2, A2);
    k_gcn_gather8<<<GN32, blk, 0, stream>>>(rowptr2, csr2, dinv2, A2, bgcn, B2);
    k_lin_tile<<<NT2, blk, 0, stream>>>(B2, Wg1h, dinv2, A2);
    k_gcn_gather8<<<GN32, blk, 0, stream>>>(rowptr2, csr2, dinv2, A2, bgcn + 64, B2);
    k_mlp_pool<<<NT2, blk, 0, stream>>>(B2, batch_a, batch_b, W1h, b1, W2h, b2, W3, b3, pool);

    k_final<<<(NG + 255) / 256, blk, 0, stream>>>(pool, (float*)d_out);
}

// Round 4
// 303.553 us; speedup vs baseline: 1.2802x; 1.1680x over previous
//
#include <hip/hip_runtime.h>
#include <hip/hip_fp16.h>
#include <math.h>

#define NN 50000
#define NE 800000
#define NG 512
#define NET (NE + NN)            // edges + self loops
#define NT2 ((2 * NN + 63) / 64) // 1563 64-node tiles over both branches
#define GN4 ((2 * NN + 3) / 4)   // wave-per-node grids
#define GN8 ((2 * NN + 7) / 8)   // 2-dst-per-wave grids
#define GN32 ((2 * NN + 31) / 32) // 8-dst-per-wave gather grids (3125, exact)
#define TS 72                    // node-major LDS stride in halfs (144B: 16B-aligned b128)

// bucket-sort CSR build
#define SLICE 512                        // dst nodes per slice
#define NSL ((NN + SLICE - 1) / SLICE)   // 98 slices per branch
#define CHK 4096                         // edges per chunk
#define NCK ((NET + CHK - 1) / CHK)      // 208 chunks per branch
#define CAP 10240                        // LDS csr buffer per slice

typedef unsigned short u16;
typedef _Float16 h8 __attribute__((ext_vector_type(8)));
typedef float f32x4 __attribute__((ext_vector_type(4)));

__device__ __forceinline__ float wsum64(float v) {
#pragma unroll
    for (int o = 32; o > 0; o >>= 1) v += __shfl_down(v, o, 64);
    return v;
}

__device__ __forceinline__ float fast_tanh(float x) {
    return 1.f - 2.f / (__expf(2.f * x) + 1.f);
}

// ---------------- CSR build: atomic-free two-level bucket sort ----------------

__global__ __launch_bounds__(256) void k_hist(const int* __restrict__ eia,
                                              const int* __restrict__ eib,
                                              int* __restrict__ cnts) {
    __shared__ int h[NSL];
    int b = blockIdx.x;
    int br = b >= NCK, c = b - (br ? NCK : 0);
    int t = threadIdx.x;
    for (int i = t; i < NSL; i += 256) h[i] = 0;
    __syncthreads();
    const int* ei = br ? eib : eia;
    int e0 = c * CHK, e1 = e0 + CHK; if (e1 > NET) e1 = NET;
    for (int e = e0 + t; e < e1; e += 256) {
        int d = (e < NE) ? __builtin_nontemporal_load(&ei[NE + e]) : (e - NE);
        atomicAdd(&h[d >> 9], 1);
    }
    __syncthreads();
    for (int i = t; i < NSL; i += 256) cnts[(br * NSL + i) * NCK + c] = h[i];
}

__global__ __launch_bounds__(64) void k_off1(int* __restrict__ cnts,
                                             int* __restrict__ sliceBase) {
    int b = blockIdx.x;                  // 2*NSL
    int br = b >= NSL, s = b - (br ? NSL : 0);
    int lane = threadIdx.x;
    int* row = cnts + (br * NSL + s) * NCK;
    int run = 0;
    for (int c0 = 0; c0 < NCK; c0 += 64) {
        int c = c0 + lane;
        int v = (c < NCK) ? row[c] : 0;
        int orig = v;
#pragma unroll
        for (int o = 1; o < 64; o <<= 1) {
            int tv = __shfl_up(v, o, 64);
            if (lane >= o) v += tv;
        }
        if (c < NCK) row[c] = run + v - orig;
        run += __shfl(v, 63, 64);
    }
    if (lane == 0) sliceBase[br * (NSL + 1) + s] = run;
}

__global__ void k_off2(int* __restrict__ sliceBase, int* __restrict__ rowptr2,
                       float* __restrict__ pool) {
    int t = threadIdx.x;  // 256
    for (int i = t; i < 4 * NG; i += 256) pool[i] = 0.f;
    if (t < 2) {
        int* sb = sliceBase + t * (NSL + 1);
        int run = 0;
        for (int s = 0; s < NSL; s++) { int v = sb[s]; sb[s] = run; run += v; }
        sb[NSL] = run;
        rowptr2[t * (NN + 1) + NN] = run;
    }
}

__global__ __launch_bounds__(256) void k_bucket(const int* __restrict__ eia,
                                                const int* __restrict__ eib,
                                                const int* __restrict__ cnts,
                                                const int* __restrict__ sliceBase,
                                                unsigned int* __restrict__ staging) {
    __shared__ int cur[NSL];
    int b = blockIdx.x;
    int br = b >= NCK, c = b - (br ? NCK : 0);
    int t = threadIdx.x;
    for (int i = t; i < NSL; i += 256)
        cur[i] = cnts[(br * NSL + i) * NCK + c] + sliceBase[br * (NSL + 1) + i];
    __syncthreads();
    const int* ei = br ? eib : eia;
    unsigned int* stg = staging + (size_t)br * NET;
    int e0 = c * CHK, e1 = e0 + CHK; if (e1 > NET) e1 = NET;
    for (int e = e0 + t; e < e1; e += 256) {
        int d, s;
        if (e < NE) {
            d = __builtin_nontemporal_load(&ei[NE + e]);
            s = __builtin_nontemporal_load(&ei[e]);
        } else { d = e - NE; s = d; }
        int pos = atomicAdd(&cur[d >> 9], 1);   // LDS atomic
        stg[pos] = ((unsigned int)(d & 511) << 16) | (unsigned int)s;
    }
}

__global__ __launch_bounds__(512) void k_slice(const unsigned int* __restrict__ staging,
                                               const int* __restrict__ sliceBase,
                                               int* __restrict__ rowptr2,
                                               float* __restrict__ dinv2,
                                               u16* __restrict__ csr2) {
    __shared__ int sc[512];
    __shared__ int cur[512];
    __shared__ u16 buf[CAP];
    int b = blockIdx.x;
    int br = b >= NSL, sl = b - (br ? NSL : 0);
    int t = threadIdx.x;
    const int* sb = sliceBase + br * (NSL + 1);
    int base = sb[sl], m = sb[sl + 1] - base;
    const unsigned int* st = staging + (size_t)br * NET + base;
    cur[t] = 0;
    __syncthreads();
    for (int i = t; i < m; i += 512) atomicAdd(&cur[st[i] >> 16], 1);
    __syncthreads();
    int v = cur[t];
    sc[t] = v;
    __syncthreads();
    for (int o = 1; o < 512; o <<= 1) {
        int add = (t >= o) ? sc[t - o] : 0;
        __syncthreads();
        sc[t] += add;
        __syncthreads();
    }
    int excl = sc[t] - v;
    int node = sl * SLICE + t;
    if (node < NN) {
        rowptr2[br * (NN + 1) + node] = base + excl;
        dinv2[br * NN + node] = v > 0 ? rsqrtf((float)v) : 0.f;
    }
    cur[t] = excl;
    __syncthreads();
    for (int i = t; i < m; i += 512) {
        unsigned int e = st[i];
        int pos = atomicAdd(&cur[e >> 16], 1);
        if (pos < CAP) buf[pos] = (u16)(e & 0xffffu);
    }
    __syncthreads();
    u16* out = csr2 + (size_t)br * NET + base;
    int mm = m < CAP ? m : CAP;
    for (int i = t; i < mm; i += 512) out[i] = buf[i];
}

// fp16 TRANSPOSED weight cache: [W1t 64x64 | W2t 32x64 | Wg0t 64x64 | Wg1t 64x64]
// Wt[n][k] = W[k][n]  ->  MFMA B-fragment is 8 contiguous halfs per lane.
__global__ __launch_bounds__(256) void k_wprep(const float* __restrict__ W1,
                                               const float* __restrict__ W2,
                                               const float* __restrict__ Wgcn,
                                               __half* __restrict__ out) {
    int i = blockIdx.x * 256 + threadIdx.x;  // 56 blocks * 256 = 14336
    float v;
    if (i < 4096)       { int n = i >> 6,        k = i & 63; v = W1[k * 64 + n]; }
    else if (i < 6144)  { int j = i - 4096; int n = j >> 6, k = j & 63; v = W2[k * 32 + n]; }
    else if (i < 10240) { int j = i - 6144; int n = j >> 6, k = j & 63; v = Wgcn[k * 64 + n]; }
    else                { int j = i - 10240; int n = j >> 6, k = j & 63; v = Wgcn[4096 + k * 64 + n]; }
    out[i] = __float2half(v);
}

// ---------------- node-level kernels (node id in [0,2*NN)) ----

__global__ void k_gat_input(const float* __restrict__ xa, const float* __restrict__ xb,
                            const float* __restrict__ Wg,
                            const float* __restrict__ avs, const float* __restrict__ avd,
                            __half* __restrict__ A, float* __restrict__ als,
                            float* __restrict__ ald) {
    __shared__ float sW[9 * 64];
    __shared__ float sas[64], sad[64];
    int t = threadIdx.x;
    for (int i = t; i < 9 * 64; i += 256) sW[i] = Wg[i];
    if (t < 64) { sas[t] = avs[t]; sad[t] = avd[t]; }
    __syncthreads();
    int n = blockIdx.x * 4 + (t >> 6);
    int u = t & 63;
    if (n >= 2 * NN) return;
    const float* xp = (n < NN) ? &xa[(size_t)n * 9] : &xb[(size_t)(n - NN) * 9];
    float h = 0.f;
#pragma unroll
    for (int f = 0; f < 9; f++) h += xp[f] * sW[f * 64 + u];
    A[(size_t)n * 64 + u] = __float2half(h);
    float ps = wsum64(h * sas[u]);
    float pd = wsum64(h * sad[u]);
    if (u == 0) { als[n] = ps; ald[n] = pd; }
}

// Normalized edge weights, CSR order: wn[j] = exp(lrelu(als[src]+ald[dst]))/den.
__global__ __launch_bounds__(256) void k_edgew(
        const int* __restrict__ rowptr2, const u16* __restrict__ csr2,
        const float* __restrict__ als, const float* __restrict__ ald,
        float* __restrict__ wn) {
    int u = threadIdx.x & 63;
    int lu = u & 31;
    int dg = blockIdx.x * 8 + (threadIdx.x >> 6) * 2 + (u >> 5);
    if (dg >= 2 * NN) return;
    int br = dg >= NN;
    int d = dg - br * NN;
    const int* rp = rowptr2 + br * (NN + 1);
    const u16* cs = csr2 + br * NET;
    float* wp = wn + (size_t)br * NET;
    int nb = br * NN;
    int beg = rp[d], end = rp[d + 1];
    float ad = ald[dg];
    float den = 0.f;
    for (int c = beg + lu; c < end; c += 32) {
        int s = nb + cs[c];
        float v = als[s] + ad;
        float w = __expf(fmaxf(v, 0.2f * v));
        den += w;
        wp[c] = w;
    }
#pragma unroll
    for (int o = 16; o > 0; o >>= 1) den += __shfl_down(den, o, 32);
    den = __shfl(den, 0, 32);
    float inv = 1.f / den;
    for (int c = beg + lu; c < end; c += 32) wp[c] *= inv;
}

// 8 halfs of a feature row, weighted-accumulated into 8 f32.
__device__ __forceinline__ void fma8(float* acc, float4 f, float w) {
    const __half2* h = (const __half2*)&f;
#pragma unroll
    for (int p = 0; p < 4; p++) {
        float2 v = __half22float2(h[p]);
        acc[2 * p]     += v.x * w;
        acc[2 * p + 1] += v.y * w;
    }
}

// GAT gather with precomputed normalized weights. 8 dsts per wave.
__global__ __launch_bounds__(256) void k_gat_gather8(
        const int* __restrict__ rowptr2, const u16* __restrict__ csr2,
        const float* __restrict__ wn, const __half* __restrict__ A,
        const float* __restrict__ bias, __half* __restrict__ B) {
    int lane = threadIdx.x & 63;
    int grp = lane >> 3, li = lane & 7;
    int dg = blockIdx.x * 32 + (threadIdx.x >> 6) * 8 + grp;  // grid exact: 3125*32=100000
    int br = dg >= NN;
    int d = dg - br * NN;
    const int* rp = rowptr2 + br * (NN + 1);
    const u16* cs = csr2 + br * NET;
    const float* wp = wn + (size_t)br * NET;
    int nb = br * NN;
    int beg = rp[d], end = rp[d + 1];
    const float4* Af = (const float4*)A;   // row = 8 float4
    float acc[8];
#pragma unroll
    for (int k = 0; k < 8; k++) acc[k] = 0.f;
    for (int j = beg; j < end; j += 4) {
        int i0 = j, i1 = j + 1, i2 = j + 2, i3 = j + 3;
        int c1 = i1 < end ? i1 : end - 1;
        int c2 = i2 < end ? i2 : end - 1;
        int c3 = i3 < end ? i3 : end - 1;
        float w0 = wp[i0];
        float w1 = i1 < end ? wp[c1] : 0.f;
        float w2 = i2 < end ? wp[c2] : 0.f;
        float w3 = i3 < end ? wp[c3] : 0.f;
        int s0 = nb + cs[i0];
        int s1 = nb + cs[c1];
        int s2 = nb + cs[c2];
        int s3 = nb + cs[c3];
        float4 f0 = Af[(size_t)s0 * 8 + li];
        float4 f1 = Af[(size_t)s1 * 8 + li];
        float4 f2 = Af[(size_t)s2 * 8 + li];
        float4 f3 = Af[(size_t)s3 * 8 + li];
        fma8(acc, f0, w0);
        fma8(acc, f1, w1);
        fma8(acc, f2, w2);
        fma8(acc, f3, w3);
    }
    const float4* bf = (const float4*)bias;
    float4 b0 = bf[2 * li], b1 = bf[2 * li + 1];
    __half2 o[4];
    o[0] = __floats2half2_rn(fast_tanh(acc[0] + b0.x), fast_tanh(acc[1] + b0.y));
    o[1] = __floats2half2_rn(fast_tanh(acc[2] + b0.z), fast_tanh(acc[3] + b0.w));
    o[2] = __floats2half2_rn(fast_tanh(acc[4] + b1.x), fast_tanh(acc[5] + b1.y));
    o[3] = __floats2half2_rn(fast_tanh(acc[6] + b1.z), fast_tanh(acc[7] + b1.w));
    ((float4*)B)[(size_t)dg * 8 + li] = *(float4*)o;
}

// GCN gather on pre-scaled Y, same 8-dst shape; mask via fma with 0/1.
__global__ __launch_bounds__(256) void k_gcn_gather8(
        const int* __restrict__ rowptr2, const u16* __restrict__ csr2,
        const float* __restrict__ dinv, const __half* __restrict__ Y,
        const float* __restrict__ bias, __half* __restrict__ Bout) {
    int lane = threadIdx.x & 63;
    int grp = lane >> 3, li = lane & 7;
    int dg = blockIdx.x * 32 + (threadIdx.x >> 6) * 8 + grp;
    int br = dg >= NN;
    int d = dg - br * NN;
    const int* rp = rowptr2 + br * (NN + 1);
    const u16* cs = csr2 + br * NET;
    int nb = br * NN;
    int beg = rp[d], end = rp[d + 1];
    const float4* Yf = (const float4*)Y;
    float acc[8];
#pragma unroll
    for (int k = 0; k < 8; k++) acc[k] = 0.f;
    for (int j = beg; j < end; j += 4) {
        int i1 = j + 1, i2 = j + 2, i3 = j + 3;
        int c1 = i1 < end ? i1 : end - 1;
        int c2 = i2 < end ? i2 : end - 1;
        int c3 = i3 < end ? i3 : end - 1;
        float w1 = i1 < end ? 1.f : 0.f;
        float w2 = i2 < end ? 1.f : 0.f;
        float w3 = i3 < end ? 1.f : 0.f;
        int s0 = nb + cs[j];
        int s1 = nb + cs[c1];
        int s2 = nb + cs[c2];
        int s3 = nb + cs[c3];
        float4 f0 = Yf[(size_t)s0 * 8 + li];
        float4 f1 = Yf[(size_t)s1 * 8 + li];
        float4 f2 = Yf[(size_t)s2 * 8 + li];
        float4 f3 = Yf[(size_t)s3 * 8 + li];
        fma8(acc, f0, 1.f);
        fma8(acc, f1, w1);
        fma8(acc, f2, w2);
        fma8(acc, f3, w3);
    }
    float dv = dinv[dg];
    const float4* bf = (const float4*)bias;
    float4 b0 = bf[2 * li], b1 = bf[2 * li + 1];
    __half2 o[4];
    o[0] = __floats2half2_rn(fast_tanh(acc[0] * dv + b0.x), fast_tanh(acc[1] * dv + b0.y));
    o[1] = __floats2half2_rn(fast_tanh(acc[2] * dv + b0.z), fast_tanh(acc[3] * dv + b0.w));
    o[2] = __floats2half2_rn(fast_tanh(acc[4] * dv + b1.x), fast_tanh(acc[5] * dv + b1.y));
    o[3] = __floats2half2_rn(fast_tanh(acc[6] * dv + b1.z), fast_tanh(acc[7] * dv + b1.w));
    ((float4*)Bout)[(size_t)dg * 8 + li] = *(float4*)o;
}

// MFMA tile GEMM: Y = dinv[n] * (X @ W), 64-node tile.
// LDS node-major [64][TS]; 4 waves, wave w owns node strip [16w,16w+16).
// Fragments per the verified m92 pattern: A row=l&15 (+strip), k=(l>>4)*8+j
// contiguous; B from TRANSPOSED weights, row=l&15 (+out-strip); D col=l&15,
// row=(l>>4)*4+reg.
__global__ __launch_bounds__(256) void k_lin_tile(
        const __half* __restrict__ X, const __half* __restrict__ Wt,
        const float* __restrict__ dinv, __half* __restrict__ Y) {
    __shared__ __half sX[64 * TS];
    __shared__ __half sW[64 * TS];
    int t = threadIdx.x;
    int base = blockIdx.x * 64;
    const float4* Xf = (const float4*)X;
    const float4* Wf = (const float4*)Wt;
#pragma unroll
    for (int rep = 0; rep < 2; rep++) {
        int i = t + rep * 256;           // 512 float4 = 64 rows x 8
        int row = i >> 3, q = i & 7;
        *(float4*)&sW[row * TS + q * 8] = Wf[i];
        float4 x;
        if (base + row < 2 * NN) x = Xf[(size_t)(base + row) * 8 + q];
        else x = make_float4(0.f, 0.f, 0.f, 0.f);
        *(float4*)&sX[row * TS + q * 8] = x;
    }
    __syncthreads();
    int l = t & 63, w = t >> 6;
    int lr = l & 15, lg = l >> 4;
    h8 av0 = *(const h8*)&sX[(16 * w + lr) * TS + 8 * lg];
    h8 av1 = *(const h8*)&sX[(16 * w + lr) * TS + 32 + 8 * lg];
    f32x4 acc[4];
#pragma unroll
    for (int s = 0; s < 4; s++) {
        h8 bv0 = *(const h8*)&sW[(16 * s + lr) * TS + 8 * lg];
        h8 bv1 = *(const h8*)&sW[(16 * s + lr) * TS + 32 + 8 * lg];
        f32x4 c = {0.f, 0.f, 0.f, 0.f};
        c = __builtin_amdgcn_mfma_f32_16x16x32_f16(av0, bv0, c, 0, 0, 0);
        c = __builtin_amdgcn_mfma_f32_16x16x32_f16(av1, bv1, c, 0, 0, 0);
        acc[s] = c;
    }
    int nrow = base + 16 * w + 4 * lg;
    float4 dv4 = *(const float4*)&dinv[16 * w + 4 * lg + base];
#pragma unroll
    for (int s = 0; s < 4; s++) {
        int col = 16 * s + lr;
#pragma unroll
        for (int i = 0; i < 4; i++) {
            int n = nrow + i;
            if (n < 2 * NN) Y[(size_t)n * 64 + col] = __float2half(acc[s][i] * dv4[i]);
        }
    }
}

// MLP (64->64 tanh ->32 tanh ->1 via W3 dot) + mean-pool, MFMA GEMMs.
__global__ __launch_bounds__(256) void k_mlp_pool(
        const __half* __restrict__ X,
        const int* __restrict__ batch_a, const int* __restrict__ batch_b,
        const __half* __restrict__ W1t, const float* __restrict__ b1,
        const __half* __restrict__ W2t, const float* __restrict__ b2,
        const float* __restrict__ W3, const float* __restrict__ b3,
        float* __restrict__ pool) {
    __shared__ __half sX[64 * TS];
    __shared__ __half sW1[64 * TS];
    __shared__ __half sW2[32 * TS];
    __shared__ float sP[64];
    __shared__ int sKey[64];
    __shared__ float sVal[64];
    int t = threadIdx.x;
    int base = blockIdx.x * 64;
    const float4* Xf = (const float4*)X;
    const float4* W1f = (const float4*)W1t;
    const float4* W2f = (const float4*)W2t;
#pragma unroll
    for (int rep = 0; rep < 2; rep++) {
        int i = t + rep * 256;
        int row = i >> 3, q = i & 7;
        *(float4*)&sW1[row * TS + q * 8] = W1f[i];
        float4 x;
        if (base + row < 2 * NN) x = Xf[(size_t)(base + row) * 8 + q];
        else x = make_float4(0.f, 0.f, 0.f, 0.f);
        *(float4*)&sX[row * TS + q * 8] = x;
    }
    {
        int row = t >> 3, q = t & 7;     // 256 float4 = 32 rows x 8
        *(float4*)&sW2[row * TS + q * 8] = W2f[t];
    }
    float bb3 = b3[0];
    __syncthreads();
    int l = t & 63, w = t >> 6;
    int lr = l & 15, lg = l >> 4;
    // ---- layer 1: 64 -> 64, tanh ----
    h8 av0 = *(const h8*)&sX[(16 * w + lr) * TS + 8 * lg];
    h8 av1 = *(const h8*)&sX[(16 * w + lr) * TS + 32 + 8 * lg];
    f32x4 d1[4];
#pragma unroll
    for (int s = 0; s < 4; s++) {
        float bias = b1[16 * s + lr];
        f32x4 c = {bias, bias, bias, bias};
        h8 bv0 = *(const h8*)&sW1[(16 * s + lr) * TS + 8 * lg];
        h8 bv1 = *(const h8*)&sW1[(16 * s + lr) * TS + 32 + 8 * lg];
        c = __builtin_amdgcn_mfma_f32_16x16x32_f16(av0, bv0, c, 0, 0, 0);
        c = __builtin_amdgcn_mfma_f32_16x16x32_f16(av1, bv1, c, 0, 0, 0);
        d1[s] = c;
    }
    // tanh back into sX (wave w touches only its own 16 rows)
#pragma unroll
    for (int s = 0; s < 4; s++) {
#pragma unroll
        for (int i = 0; i < 4; i++) {
            sX[(16 * w + 4 * lg + i) * TS + 16 * s + lr] = __float2half(fast_tanh(d1[s][i]));
        }
    }
    __syncthreads();
    // ---- layer 2: 64 -> 32, tanh; then dot with W3 ----
    h8 a20 = *(const h8*)&sX[(16 * w + lr) * TS + 8 * lg];
    h8 a21 = *(const h8*)&sX[(16 * w + lr) * TS + 32 + 8 * lg];
    f32x4 d2[2];
#pragma unroll
    for (int s = 0; s < 2; s++) {
        float bias = b2[16 * s + lr];
        f32x4 c = {bias, bias, bias, bias};
        h8 bv0 = *(const h8*)&sW2[(16 * s + lr) * TS + 8 * lg];
        h8 bv1 = *(const h8*)&sW2[(16 * s + lr) * TS + 32 + 8 * lg];
        c = __builtin_amdgcn_mfma_f32_16x16x32_f16(a20, bv0, c, 0, 0, 0);
        c = __builtin_amdgcn_mfma_f32_16x16x32_f16(a21, bv1, c, 0, 0, 0);
        d2[s] = c;
    }
    float w3a = W3[lr], w3b = W3[16 + lr];
    float pr[4];
#pragma unroll
    for (int i = 0; i < 4; i++)
        pr[i] = fast_tanh(d2[0][i]) * w3a + fast_tanh(d2[1][i]) * w3b;
#pragma unroll
    for (int o = 1; o < 16; o <<= 1) {
#pragma unroll
        for (int i = 0; i < 4; i++) pr[i] += __shfl_xor(pr[i], o, 16);
    }
    if (lr == 0) {
#pragma unroll
        for (int i = 0; i < 4; i++) sP[16 * w + 4 * lg + i] = pr[i];
    }
    __syncthreads();
    // ---- mean-pool: segmented-run atomics over 64 sorted nodes ----
    if (t < 64) {
        int n = base + t;
        bool valid = n < 2 * NN;
        int br = n >= NN;
        int g = valid ? (br ? batch_b[n - NN] : batch_a[n]) : -1;
        int key = valid ? (br * 4096 + g) : -1;
        sKey[t] = key;
        sVal[t] = sP[t] + bb3;
        __builtin_amdgcn_s_barrier();
        if (valid && (t == 0 || sKey[t - 1] != key)) {
            float sum = 0.f;
            int cnt = 0;
            for (int j = t; j < 64 && sKey[j] == key; j++) { sum += sVal[j]; cnt++; }
            float* bin = pool + br * 2 * NG;
            atomicAdd(&bin[g], sum);
            atomicAdd(&bin[NG + g], (float)cnt);
        }
    }
}

// pool layout: [sa(NG), ca(NG), sb(NG), cb(NG)]
__global__ void k_final(const float* __restrict__ pool, float* __restrict__ out) {
    int g = blockIdx.x * 256 + threadIdx.x;
    if (g >= NG) return;
    float ua = pool[g] / fmaxf(pool[NG + g], 1.f);
    float ub = pool[2 * NG + g] / fmaxf(pool[3 * NG + g], 1.f);
    float z = ub - ua;
    out[g] = 1.f / (1.f + __expf(-z));
}

extern "C" void kernel_launch(void* const* d_in, const int* in_sizes, int n_in,
                              void* d_out, int out_size, void* d_ws, size_t ws_size,
                              hipStream_t stream) {
    const float* x_a = (const float*)d_in[0];
    const float* x_b = (const float*)d_in[1];
    const int* ei_a = (const int*)d_in[2];
    const int* ei_b = (const int*)d_in[3];
    const int* batch_a = (const int*)d_in[4];
    const int* batch_b = (const int*)d_in[5];
    const float* Wg   = (const float*)d_in[6];
    const float* avs  = (const float*)d_in[7];
    const float* avd  = (const float*)d_in[8];
    const float* bg   = (const float*)d_in[9];
    const float* Wgcn = (const float*)d_in[10];
    const float* bgcn = (const float*)d_in[11];
    const float* W1 = (const float*)d_in[12];
    const float* b1 = (const float*)d_in[13];
    const float* W2 = (const float*)d_in[14];
    const float* b2 = (const float*)d_in[15];
    const float* W3 = (const float*)d_in[16];
    const float* b3 = (const float*)d_in[17];

    char* w = (char*)d_ws;
    __half* A2 = (__half*)w;          w += (size_t)2 * NN * 64 * 2;   // 12.8 MB
    __half* B2 = (__half*)w;          w += (size_t)2 * NN * 64 * 2;   // 12.8 MB
    float* als2 = (float*)w;          w += (size_t)2 * NN * 4;
    float* ald2 = (float*)w;          w += (size_t)2 * NN * 4;
    float* dinv2 = (float*)w;         w += (size_t)2 * NN * 4;
    float* pool = (float*)w;          w += (size_t)4 * NG * 4;
    int* rowptr2 = (int*)w;           w += (size_t)2 * (NN + 1) * 4;
    int* cnts = (int*)w;              w += (size_t)2 * NSL * NCK * 4; // 163 KB
    int* sliceBase = (int*)w;         w += (size_t)2 * (NSL + 1) * 4;
    u16* csr2 = (u16*)w;              w += (size_t)2 * NET * 2;       // 3.4 MB
    float* wn = (float*)w;            w += (size_t)2 * NET * 4;       // 6.8 MB
    __half* wcache = (__half*)w;      w += (size_t)14336 * 2;         // 28 KB
    // staging (2*NET u32 = 6.8 MB) aliases A2: dead before k_gat_input writes A2
    unsigned int* staging = (unsigned int*)A2;

    __half* W1t = wcache;
    __half* W2t = wcache + 4096;
    __half* Wg0t = wcache + 6144;
    __half* Wg1t = wcache + 10240;

    dim3 blk(256);

    // CSR build: atomic-free bucket sort
    k_hist<<<2 * NCK, blk, 0, stream>>>(ei_a, ei_b, cnts);
    k_wprep<<<56, blk, 0, stream>>>(W1, W2, Wgcn, wcache);
    k_off1<<<2 * NSL, dim3(64), 0, stream>>>(cnts, sliceBase);
    k_off2<<<1, blk, 0, stream>>>(sliceBase, rowptr2, pool);
    k_bucket<<<2 * NCK, blk, 0, stream>>>(ei_a, ei_b, cnts, sliceBase, staging);
    k_slice<<<2 * NSL, dim3(512), 0, stream>>>(staging, sliceBase, rowptr2, dinv2, csr2);

    k_gat_input<<<GN4, blk, 0, stream>>>(x_a, x_b, Wg, avs, avd, A2, als2, ald2);
    k_edgew<<<GN8, blk, 0, stream>>>(rowptr2, csr2, als2, ald2, wn);
    k_gat_gather8<<<GN32, blk, 0, stream>>>(rowptr2, csr2, wn, A2, bg, B2);
    k_lin_tile<<<NT2, blk, 0, stream>>>(B2, Wg0t, dinv2, A2);
    k_gcn_gather8<<<GN32, blk, 0, stream>>>(rowptr2, csr2, dinv2, A2, bgcn, B2);
    k_lin_tile<<<NT2, blk, 0, stream>>>(B2, Wg1t, dinv2, A2);
    k_gcn_gather8<<<GN32, blk, 0, stream>>>(rowptr2, csr2, dinv2, A2, bgcn + 64, B2);
    k_mlp_pool<<<NT2, blk, 0, stream>>>(B2, batch_a, batch_b, W1t, b1, W2t, b2, W3, b3, pool);

    k_final<<<(NG + 255) / 256, blk, 0, stream>>>(pool, (float*)d_out);
}